// Round 1
// baseline (1019.204 us; speedup 1.0000x reference)
//
#include <hip/hip_runtime.h>
#include <hip/hip_bf16.h>

#define F_IN    256
#define D_HID   64
#define H_HEADS 8
#define NC      10
#define ALPHA   0.2f
#define SCAN_T  1024

typedef __attribute__((ext_vector_type(8))) short short8;
typedef __attribute__((ext_vector_type(4))) float f32x4;

// ---------- bf16 helpers ----------
__device__ __forceinline__ float bfu2f(unsigned short u) {
    union { float f; unsigned int i; } c; c.i = ((unsigned int)u) << 16; return c.f;
}
__device__ __forceinline__ unsigned short f2bfu(float f) {
    union { float f; unsigned int i; } c; c.f = f;
    unsigned int x = c.i;
    x += 0x7fffu + ((x >> 16) & 1u);   // round-to-nearest-even
    return (unsigned short)(x >> 16);
}

// ---------- inline dtype detection (f32 vs bf16 storage), wave-uniform ----------
// MUST run with ALL 64 lanes active (__ballot counts active lanes only).
__device__ __forceinline__ bool detect_f32(const void* xraw) {
    unsigned int w = ((const unsigned int*)xraw)[threadIdx.x & 63];
    unsigned int e = (w >> 7) & 0xffu;
    unsigned long long m = __ballot(e >= 140u);
    return __popcll(m) > 8;
}

// ---------- fused prep: all input conversions + edge histogram ----------
__global__ __launch_bounds__(256) void prep_kernel(
    const void* __restrict__ x_raw,  unsigned short* __restrict__ x_bf,
    const void* __restrict__ Wh_raw, unsigned short* __restrict__ wh_f,
    const void* __restrict__ ah_raw, float* __restrict__ ah32,
    const void* __restrict__ Wo_raw, float* __restrict__ Wo32,
    const void* __restrict__ ao_raw, float* __restrict__ ao32,
    const int* __restrict__ esrc, int* __restrict__ counts,
    int N, int E, int bx, int bw, int ba, int bo)
{
    int b = blockIdx.x;
    bool isf32 = detect_f32(x_raw);   // all lanes active here
    if (b < bx) {                       // x -> bf16, 8 elems/thread
        long i = (long)b * 256 + threadIdx.x;
        long n8 = (long)N * F_IN / 8;
        if (i < n8) {
            unsigned short o[8];
            if (isf32) {
                const float4* s = (const float4*)x_raw + i * 2;
                float4 a = s[0], bb = s[1];
                o[0] = f2bfu(a.x);  o[1] = f2bfu(a.y);
                o[2] = f2bfu(a.z);  o[3] = f2bfu(a.w);
                o[4] = f2bfu(bb.x); o[5] = f2bfu(bb.y);
                o[6] = f2bfu(bb.z); o[7] = f2bfu(bb.w);
            } else {
                *(uint4*)o = ((const uint4*)x_raw)[i];
            }
            *(uint4*)(x_bf + i * 8) = *(uint4*)o;
        }
    } else if (b < bw) {                // W_heads [8][256][64] -> fragment-major bf16
        int i = (b - bx) * 256 + threadIdx.x;
        int d = i & 63, k = (i >> 6) & 255, h = i >> 14;
        float v = isf32 ? ((const float*)Wh_raw)[i] : bfu2f(((const unsigned short*)Wh_raw)[i]);
        int ks = k >> 5, q = (k >> 3) & 3, j = k & 7;
        int c = d >> 4, m = d & 15;
        wh_f[(((h * 8 + ks) * 4 + c) << 9) + (q * 16 + m) * 8 + j] = f2bfu(v);
    } else if (b < ba) {                // a_heads -> f32 (1024)
        int i = (b - bw) * 256 + threadIdx.x;
        ah32[i] = isf32 ? ((const float*)ah_raw)[i] : bfu2f(((const unsigned short*)ah_raw)[i]);
    } else if (b < bo) {                // W_out -> f32 (5120)
        int i = (b - ba) * 256 + threadIdx.x;
        Wo32[i] = isf32 ? ((const float*)Wo_raw)[i] : bfu2f(((const unsigned short*)Wo_raw)[i]);
    } else if (b == bo) {               // a_out -> f32 (20)
        int i = threadIdx.x;
        if (i < 2 * NC)
            ao32[i] = isf32 ? ((const float*)ao_raw)[i] : bfu2f(((const unsigned short*)ao_raw)[i]);
    } else {                            // edge histogram
        int e = (b - bo - 1) * 256 + threadIdx.x;
        if (e < E) atomicAdd(&counts[esrc[e]], 1);
    }
}

// ---------- CSR scan ----------
__global__ __launch_bounds__(SCAN_T) void scan_kernel(
    const int* __restrict__ counts, int* __restrict__ row_start, int N, int E)
{
    __shared__ int sums[SCAN_T];
    int t = threadIdx.x;
    int chunk = (N + SCAN_T - 1) / SCAN_T;
    int b = t * chunk, e = min(b + chunk, N);
    int s = 0;
    for (int i = b; i < e; ++i) s += counts[i];
    sums[t] = s;
    __syncthreads();
    for (int off = 1; off < SCAN_T; off <<= 1) {
        int u = (t >= off) ? sums[t - off] : 0;
        __syncthreads();
        sums[t] += u;
        __syncthreads();
    }
    int running = sums[t] - s;
    for (int i = b; i < e; ++i) { row_start[i] = running; running += counts[i]; }
    if (t == SCAN_T - 1) row_start[N] = E;
}

// ---------- lean CSR scatter: coalesced reads, one atomic, one 4B scatter ----------
__global__ __launch_bounds__(256) void scatter_kernel(
    const int* __restrict__ src, const int* __restrict__ dst,
    const int* __restrict__ row_start, int* __restrict__ cursor,
    int* __restrict__ csr_dst, int E)
{
    int e = blockIdx.x * 256 + threadIdx.x;
    if (e >= E) return;
    int s = src[e];
    int pos = atomicAdd(&cursor[s], 1);
    csr_dst[row_start[s] + pos] = dst[e];
}

// ---------- layer-1 MFMA GEMM + fused attn1 (fragment-major B, 2 heads/block) ----------
// Output layout changed: hh[16][N][32] bf16 (slice = head*2 + half), so the
// edge-aggregation pass can work on 3.2 MB L2-resident slices.
__global__ __launch_bounds__(256) void gemm1_kernel(
    const unsigned short* __restrict__ x_bf,   // [N,256] bf16
    const unsigned short* __restrict__ wh_f,   // fragment-major bf16
    const float* __restrict__ ah,              // [8,128] f32
    unsigned short* __restrict__ hh,           // [16][N][32] bf16 out
    float* __restrict__ s1s, float* __restrict__ s1d, int N)
{
    __shared__ unsigned short Os[64][72];

    const int t = threadIdx.x;
    const int w = t >> 6, lane = t & 63;
    const int q = lane >> 4, m = lane & 15;
    const int n0 = blockIdx.x * 64;
    const int h0 = blockIdx.y * 2;

    int r = n0 + 16 * w + m;
    const unsigned short* xr = x_bf + (long)(r < N ? r : N - 1) * 256;
    short8 afrag[8];
    #pragma unroll
    for (int ks = 0; ks < 8; ++ks)
        afrag[ks] = *(const short8*)(xr + ks * 32 + q * 8);

    #pragma unroll
    for (int hi = 0; hi < 2; ++hi) {
        const int h = h0 + hi;
        f32x4 acc[4] = {};
        const unsigned short* Bh = wh_f + (((long)h * 32) << 9);
        #pragma unroll
        for (int ks = 0; ks < 8; ++ks) {
            #pragma unroll
            for (int c = 0; c < 4; ++c) {
                short8 b = *(const short8*)(Bh + (((ks * 4 + c) << 9) + lane * 8));
                acc[c] = __builtin_amdgcn_mfma_f32_16x16x32_bf16(afrag[ks], b, acc[c], 0, 0, 0);
            }
        }

        const float* a1 = ah + h * 128;
        float a1m = a1[m], a1m16 = a1[16 + m], a1m32 = a1[32 + m], a1m48 = a1[48 + m];
        float a2m = a1[64 + m], a2m16 = a1[80 + m], a2m32 = a1[96 + m], a2m48 = a1[112 + m];
        #pragma unroll
        for (int reg = 0; reg < 4; ++reg) {
            float p1 = acc[0][reg] * a1m + acc[1][reg] * a1m16 + acc[2][reg] * a1m32 + acc[3][reg] * a1m48;
            float p2 = acc[0][reg] * a2m + acc[1][reg] * a2m16 + acc[2][reg] * a2m32 + acc[3][reg] * a2m48;
            #pragma unroll
            for (int off = 1; off < 16; off <<= 1) {
                p1 += __shfl_xor(p1, off);
                p2 += __shfl_xor(p2, off);
            }
            int row = n0 + 16 * w + q * 4 + reg;
            if (m == 0 && row < N) {
                s1s[row * 8 + h] = p1;
                s1d[row * 8 + h] = p2;
            }
        }

        #pragma unroll
        for (int c = 0; c < 4; ++c)
            #pragma unroll
            for (int reg = 0; reg < 4; ++reg)
                Os[16 * w + q * 4 + reg][c * 16 + m] = f2bfu(acc[c][reg]);
        // write back in slice-major layout: slice = h*2+half, row n, 32 dims (64 B)
        #pragma unroll
        for (int half = 0; half < 2; ++half) {
            int row = lane >> 2, quad = lane & 3;
            int rr = n0 + 16 * w + row;
            if (rr < N)
                *(uint4*)(hh + ((long)(h * 2 + half) * N + rr) * 32 + quad * 8) =
                    *(const uint4*)&Os[16 * w + row][half * 32 + quad * 8];
        }
    }
}

// ---------- pass A: per-edge attention weights (all 8 heads) + 1/rowsum ----------
// Gathers only s1d (1.6 MB, fully L2-resident). Lane = (edge slot j=lane>>3, head h=lane&7).
__global__ __launch_bounds__(256) void ev_kernel(
    const int* __restrict__ row_start, const int* __restrict__ csr_dst,
    const float* __restrict__ s1s, const float* __restrict__ s1d,
    float* __restrict__ ev_g,          // [8][E] f32
    float* __restrict__ rsinv,         // [N*8] f32
    int N, int E)
{
    int n = blockIdx.x * 4 + (threadIdx.x >> 6);
    if (n >= N) return;
    int lane = threadIdx.x & 63;
    int j = lane >> 3, h = lane & 7;
    int beg = row_start[n], end = row_start[n + 1];
    float ss = s1s[n * 8 + h];
    float rs = 0.f;
    for (int i0 = beg; i0 < end; i0 += 8) {
        int i = i0 + j;
        if (i < end) {
            int d = csr_dst[i];
            float sc = ss + s1d[d * 8 + h];
            float lr = sc > 0.f ? sc : ALPHA * sc;
            float ev = __expf(-lr);
            rs += ev;
            __builtin_nontemporal_store(ev, &ev_g[(long)h * E + i]);
        }
    }
    rs += __shfl_xor(rs, 8);
    rs += __shfl_xor(rs, 16);
    rs += __shfl_xor(rs, 32);
    if (j == 0) rsinv[n * 8 + h] = 1.f / rs;
}

// ---------- pass B: sliced aggregation, 16 slices x 32 dims (3.2 MB L2-resident) ----------
// grid = (ceil(N/4), 16); blockIdx.y = slice (head = y>>1, half = y&1).
// Wave per node: lane = (edge slot j=lane>>4, dim-pair c=lane&15).
// Per edge: one 64 B line from the slice table (L2 hit), ev/csr streamed NT.
__global__ __launch_bounds__(256) void agg1_kernel(
    const int* __restrict__ row_start, const int* __restrict__ csr_dst,
    const float* __restrict__ ev_g,        // [8][E]
    const float* __restrict__ rsinv,       // [N*8]
    const unsigned short* __restrict__ hh, // [16][N][32] bf16
    unsigned short* __restrict__ xcat,     // [N,512] bf16 out
    int N, int E)
{
    int p = blockIdx.y;
    int n = blockIdx.x * 4 + (threadIdx.x >> 6);
    if (n >= N) return;
    int lane = threadIdx.x & 63;
    int j = lane >> 4, c = lane & 15;
    int beg = row_start[n], end = row_start[n + 1];
    const float* evp = ev_g + (long)(p >> 1) * E;
    const unsigned int* hb = (const unsigned int*)hh + (long)p * N * 16;
    float a0 = 0.f, a1 = 0.f;
    for (int i0 = beg; i0 < end; i0 += 4) {
        int i = i0 + j;
        if (i < end) {
            int d = __builtin_nontemporal_load(&csr_dst[i]);
            float ev = __builtin_nontemporal_load(&evp[i]);
            unsigned int wv = hb[(long)d * 16 + c];
            a0 += ev * bfu2f((unsigned short)(wv & 0xffffu));
            a1 += ev * bfu2f((unsigned short)(wv >> 16));
        }
    }
    a0 += __shfl_xor(a0, 16); a0 += __shfl_xor(a0, 32);
    a1 += __shfl_xor(a1, 16); a1 += __shfl_xor(a1, 32);
    if (j == 0) {
        float inv = rsinv[n * 8 + (p >> 1)];
        float v0 = a0 * inv, v1 = a1 * inv;
        v0 = v0 > 0.f ? v0 : __expf(v0) - 1.f;   // elu
        v1 = v1 > 0.f ? v1 : __expf(v1) - 1.f;
        unsigned int o = (unsigned int)f2bfu(v0) | ((unsigned int)f2bfu(v1) << 16);
        __builtin_nontemporal_store(o,
            (unsigned int*)xcat + (long)n * 256 + (p >> 1) * 32 + (p & 1) * 16 + c);
    }
}

// ---------- layer-2 GEMM + fused attn2: 2 threads per node (split-k) ----------
__global__ __launch_bounds__(256) void gemm2_kernel(
    const unsigned short* __restrict__ xcat_bf, // [N,512] bf16
    const float* __restrict__ Wo,               // [512,10] f32
    const float* __restrict__ ao,               // [20] f32
    float* __restrict__ h2p,                    // [N,16] f32, pad=0
    float* __restrict__ s2s, float* __restrict__ s2d, int N)
{
    int tid = blockIdx.x * 256 + threadIdx.x;
    int n = tid >> 1;
    if (n >= N) return;
    int half = tid & 1;
    float acc[NC];
    #pragma unroll
    for (int c = 0; c < NC; ++c) acc[c] = 0.f;
    const uint4* xp = (const uint4*)(xcat_bf + (long)n * 512) + half * 32;
    for (int k8 = 0; k8 < 32; ++k8) {
        uint4 w = xp[k8];
        float f[8];
        f[0] = bfu2f((unsigned short)(w.x & 0xffffu)); f[1] = bfu2f((unsigned short)(w.x >> 16));
        f[2] = bfu2f((unsigned short)(w.y & 0xffffu)); f[3] = bfu2f((unsigned short)(w.y >> 16));
        f[4] = bfu2f((unsigned short)(w.z & 0xffffu)); f[5] = bfu2f((unsigned short)(w.z >> 16));
        f[6] = bfu2f((unsigned short)(w.w & 0xffffu)); f[7] = bfu2f((unsigned short)(w.w >> 16));
        #pragma unroll
        for (int u = 0; u < 8; ++u) {
            const float* wr = Wo + ((half * 32 + k8) * 8 + u) * NC;
            #pragma unroll
            for (int c = 0; c < NC; ++c) acc[c] += f[u] * wr[c];
        }
    }
    #pragma unroll
    for (int c = 0; c < NC; ++c) acc[c] += __shfl_xor(acc[c], 1, 64);
    if (half == 0) {
        float s1 = 0.f, s2 = 0.f;
        *(float4*)(h2p + (long)n * 16)      = make_float4(acc[0], acc[1], acc[2], acc[3]);
        *(float4*)(h2p + (long)n * 16 + 4)  = make_float4(acc[4], acc[5], acc[6], acc[7]);
        *(float4*)(h2p + (long)n * 16 + 8)  = make_float4(acc[8], acc[9], 0.f, 0.f);
        *(float4*)(h2p + (long)n * 16 + 12) = make_float4(0.f, 0.f, 0.f, 0.f);
        #pragma unroll
        for (int c = 0; c < NC; ++c) {
            s1 += acc[c] * ao[c];
            s2 += acc[c] * ao[NC + c];
        }
        s2s[n] = s1;
        s2d[n] = s2;
    }
}

// ---------- layer-2 CSR gather: wave per node, lane=(edge-slot j, class c) ----------
__global__ __launch_bounds__(256) void edge_agg2_kernel(
    const int* __restrict__ row_start, const int* __restrict__ csr_dst,
    const float* __restrict__ h2p,             // [N,16] f32, pad=0
    const float* __restrict__ s_src2, const float* __restrict__ s_dst2,
    void* __restrict__ out, const void* __restrict__ x_raw, int N)
{
    bool isf32 = detect_f32(x_raw);   // all lanes active
    int lane = threadIdx.x & 63;
    int n = blockIdx.x * 4 + (threadIdx.x >> 6);
    if (n >= N) return;
    int c = lane & 15, j = lane >> 4;   // 4 edge slots x 16 classes(padded)
    int beg = row_start[n], end = row_start[n + 1];
    float ss = s_src2[n];
    float rs = 0.f, acc = 0.f;
    for (int i0 = beg; i0 < end; i0 += 4) {
        int i = i0 + j;
        if (i < end) {
            int d = csr_dst[i];
            float sc = ss + s_dst2[d];
            float lr = sc > 0.f ? sc : ALPHA * sc;
            float ev = __expf(-lr);
            rs += ev;
            acc += ev * h2p[(long)d * 16 + c];
        }
    }
    rs  += __shfl_xor(rs, 16, 64);  rs  += __shfl_xor(rs, 32, 64);
    acc += __shfl_xor(acc, 16, 64); acc += __shfl_xor(acc, 32, 64);
    float v = acc / rs;
    v = v > 0.f ? v : __expf(v) - 1.f;           // elu
    float vm = (c < NC) ? v : -1e30f;
    #pragma unroll
    for (int off = 1; off < 16; off <<= 1) vm = fmaxf(vm, __shfl_xor(vm, off, 64));
    float ex = (c < NC) ? __expf(v - vm) : 0.f;
    #pragma unroll
    for (int off = 1; off < 16; off <<= 1) ex += __shfl_xor(ex, off, 64);
    float lse = vm + logf(ex);
    if (c < NC && j == 0) {
        if (isf32) ((float*)out)[(long)n * NC + c] = v - lse;
        else       ((unsigned short*)out)[(long)n * NC + c] = f2bfu(v - lse);
    }
}

extern "C" void kernel_launch(void* const* d_in, const int* in_sizes, int n_in,
                              void* d_out, int out_size, void* d_ws, size_t ws_size,
                              hipStream_t stream)
{
    const void* x_raw  = d_in[0];
    const int*  esrc   = (const int*)d_in[1];
    const int*  edst   = (const int*)d_in[2];
    const void* Wh_raw = d_in[3];
    const void* ah_raw = d_in[4];
    const void* Wo_raw = d_in[5];
    const void* ao_raw = d_in[6];

    const int N = in_sizes[0] / F_IN;
    const int E = in_sizes[1];

    char* ws = (char*)d_ws;
    size_t off = 0;
    auto alloc = [&](size_t bytes) -> void* {
        void* p = ws + off;
        off = (off + bytes + 255) & ~(size_t)255;
        return p;
    };
    // zero-init region first (counts|cursor contiguous -> ONE memset)
    int*            counts    = (int*)           alloc((size_t)N * 4);
    int*            cursor    = (int*)           alloc((size_t)N * 4);
    size_t clear_span = (size_t)((char*)cursor + (size_t)N * 4 - (char*)counts);

    unsigned short* x_bf      = (unsigned short*)alloc((size_t)N * F_IN * 2);
    unsigned short* wh_f      = (unsigned short*)alloc((size_t)H_HEADS * D_HID * F_IN * 2);
    float*          ah32      = (float*)         alloc((size_t)H_HEADS * 2 * D_HID * 4);
    float*          Wo32      = (float*)         alloc((size_t)512 * NC * 4);
    float*          ao32      = (float*)         alloc((size_t)2 * NC * 4);
    unsigned short* hh        = (unsigned short*)alloc((size_t)N * 512 * 2);   // [16][N][32]
    unsigned short* xcat_bf   = (unsigned short*)alloc((size_t)N * 512 * 2);
    float*          s1s       = (float*)         alloc((size_t)N * 8 * 4);
    float*          s1d       = (float*)         alloc((size_t)N * 8 * 4);
    float*          h2p       = (float*)         alloc((size_t)N * 16 * 4);
    float*          s2s       = (float*)         alloc((size_t)N * 4);
    float*          s2d       = (float*)         alloc((size_t)N * 4);
    int*            row_start = (int*)           alloc((size_t)(N + 1) * 4);
    int*            csr_dst   = (int*)           alloc((size_t)E * 4);
    float*          ev_g      = (float*)         alloc((size_t)H_HEADS * E * 4);
    float*          rsinv     = (float*)         alloc((size_t)N * 8 * 4);
    (void)ws_size;

    hipMemsetAsync(counts, 0, clear_span, stream);

    // fused converts + histogram (dtype detected per-block from x sample)
    int bx = (int)(((long)N * F_IN / 8 + 255) / 256);      // x blocks
    int bw = bx + (H_HEADS * F_IN * D_HID) / 256;          // + W frag blocks
    int ba = bw + (H_HEADS * 2 * D_HID) / 256;             // + ah blocks
    int bo = ba + (512 * NC) / 256;                        // + Wo blocks; bo = ao block
    int nb = bo + 1 + (E + 255) / 256;                     // + hist blocks
    prep_kernel<<<nb, 256, 0, stream>>>(x_raw, x_bf, Wh_raw, wh_f, ah_raw, ah32,
                                        Wo_raw, Wo32, ao_raw, ao32,
                                        esrc, counts, N, E, bx, bw, ba, bo);
    scan_kernel<<<1, SCAN_T, 0, stream>>>(counts, row_start, N, E);
    scatter_kernel<<<(E + 255) / 256, 256, 0, stream>>>(esrc, edst, row_start, cursor, csr_dst, E);

    // layer 1
    dim3 g1((N + 63) / 64, H_HEADS / 2);
    gemm1_kernel<<<g1, 256, 0, stream>>>(x_bf, wh_f, ah32, hh, s1s, s1d, N);
    ev_kernel<<<(N + 3) / 4, 256, 0, stream>>>(row_start, csr_dst, s1s, s1d, ev_g, rsinv, N, E);
    dim3 gB((N + 3) / 4, 16);
    agg1_kernel<<<gB, 256, 0, stream>>>(row_start, csr_dst, ev_g, rsinv, hh, xcat_bf, N, E);

    // layer 2
    gemm2_kernel<<<(2 * N + 255) / 256, 256, 0, stream>>>(xcat_bf, Wo32, ao32, h2p, s2s, s2d, N);
    edge_agg2_kernel<<<(N + 3) / 4, 256, 0, stream>>>(row_start, csr_dst, h2p, s2s, s2d, d_out, x_raw, N);
}

// Round 2
// 538.709 us; speedup vs baseline: 1.8919x; 1.8919x over previous
//
#include <hip/hip_runtime.h>
#include <hip/hip_bf16.h>

#define F_IN    256
#define D_HID   64
#define H_HEADS 8
#define NC      10
#define ALPHA   0.2f
#define SCAN_T  1024

typedef __attribute__((ext_vector_type(8))) short short8;
typedef __attribute__((ext_vector_type(4))) float f32x4;

// ---------- bf16 helpers ----------
__device__ __forceinline__ float bfu2f(unsigned short u) {
    union { float f; unsigned int i; } c; c.i = ((unsigned int)u) << 16; return c.f;
}
__device__ __forceinline__ unsigned short f2bfu(float f) {
    union { float f; unsigned int i; } c; c.f = f;
    unsigned int x = c.i;
    x += 0x7fffu + ((x >> 16) & 1u);   // round-to-nearest-even
    return (unsigned short)(x >> 16);
}

// ---------- inline dtype detection (f32 vs bf16 storage), wave-uniform ----------
// MUST run with ALL 64 lanes active (__ballot counts active lanes only).
__device__ __forceinline__ bool detect_f32(const void* xraw) {
    unsigned int w = ((const unsigned int*)xraw)[threadIdx.x & 63];
    unsigned int e = (w >> 7) & 0xffu;
    unsigned long long m = __ballot(e >= 140u);
    return __popcll(m) > 8;
}

// ---------- fused prep: all input conversions + edge histogram ----------
__global__ __launch_bounds__(256) void prep_kernel(
    const void* __restrict__ x_raw,  unsigned short* __restrict__ x_bf,
    const void* __restrict__ Wh_raw, unsigned short* __restrict__ wh_f,
    const void* __restrict__ ah_raw, float* __restrict__ ah32,
    const void* __restrict__ Wo_raw, float* __restrict__ Wo32,
    const void* __restrict__ ao_raw, float* __restrict__ ao32,
    const int* __restrict__ esrc, int* __restrict__ counts,
    int N, int E, int bx, int bw, int ba, int bo)
{
    int b = blockIdx.x;
    bool isf32 = detect_f32(x_raw);   // all lanes active here
    if (b < bx) {                       // x -> bf16, 8 elems/thread
        long i = (long)b * 256 + threadIdx.x;
        long n8 = (long)N * F_IN / 8;
        if (i < n8) {
            unsigned short o[8];
            if (isf32) {
                const float4* s = (const float4*)x_raw + i * 2;
                float4 a = s[0], bb = s[1];
                o[0] = f2bfu(a.x);  o[1] = f2bfu(a.y);
                o[2] = f2bfu(a.z);  o[3] = f2bfu(a.w);
                o[4] = f2bfu(bb.x); o[5] = f2bfu(bb.y);
                o[6] = f2bfu(bb.z); o[7] = f2bfu(bb.w);
            } else {
                *(uint4*)o = ((const uint4*)x_raw)[i];
            }
            *(uint4*)(x_bf + i * 8) = *(uint4*)o;
        }
    } else if (b < bw) {                // W_heads [8][256][64] -> fragment-major bf16
        int i = (b - bx) * 256 + threadIdx.x;
        int d = i & 63, k = (i >> 6) & 255, h = i >> 14;
        float v = isf32 ? ((const float*)Wh_raw)[i] : bfu2f(((const unsigned short*)Wh_raw)[i]);
        int ks = k >> 5, q = (k >> 3) & 3, j = k & 7;
        int c = d >> 4, m = d & 15;
        wh_f[(((h * 8 + ks) * 4 + c) << 9) + (q * 16 + m) * 8 + j] = f2bfu(v);
    } else if (b < ba) {                // a_heads -> f32 (1024)
        int i = (b - bw) * 256 + threadIdx.x;
        ah32[i] = isf32 ? ((const float*)ah_raw)[i] : bfu2f(((const unsigned short*)ah_raw)[i]);
    } else if (b < bo) {                // W_out -> f32 (5120)
        int i = (b - ba) * 256 + threadIdx.x;
        Wo32[i] = isf32 ? ((const float*)Wo_raw)[i] : bfu2f(((const unsigned short*)Wo_raw)[i]);
    } else if (b == bo) {               // a_out -> f32 (20)
        int i = threadIdx.x;
        if (i < 2 * NC)
            ao32[i] = isf32 ? ((const float*)ao_raw)[i] : bfu2f(((const unsigned short*)ao_raw)[i]);
    } else {                            // edge histogram
        int e = (b - bo - 1) * 256 + threadIdx.x;
        if (e < E) atomicAdd(&counts[esrc[e]], 1);
    }
}

// ---------- CSR scan ----------
__global__ __launch_bounds__(SCAN_T) void scan_kernel(
    const int* __restrict__ counts, int* __restrict__ row_start, int N, int E)
{
    __shared__ int sums[SCAN_T];
    int t = threadIdx.x;
    int chunk = (N + SCAN_T - 1) / SCAN_T;
    int b = t * chunk, e = min(b + chunk, N);
    int s = 0;
    for (int i = b; i < e; ++i) s += counts[i];
    sums[t] = s;
    __syncthreads();
    for (int off = 1; off < SCAN_T; off <<= 1) {
        int u = (t >= off) ? sums[t - off] : 0;
        __syncthreads();
        sums[t] += u;
        __syncthreads();
    }
    int running = sums[t] - s;
    for (int i = b; i < e; ++i) { row_start[i] = running; running += counts[i]; }
    if (t == SCAN_T - 1) row_start[N] = E;
}

// ---------- lean CSR scatter: coalesced reads, one atomic, one 4B scatter ----------
__global__ __launch_bounds__(256) void scatter_kernel(
    const int* __restrict__ src, const int* __restrict__ dst,
    const int* __restrict__ row_start, int* __restrict__ cursor,
    int* __restrict__ csr_dst, int E)
{
    int e = blockIdx.x * 256 + threadIdx.x;
    if (e >= E) return;
    int s = src[e];
    int pos = atomicAdd(&cursor[s], 1);
    csr_dst[row_start[s] + pos] = dst[e];
}

// ---------- layer-1 MFMA GEMM + fused attn1 (fragment-major B, 4 heads/block) ----------
__global__ __launch_bounds__(256) void gemm1_kernel(
    const unsigned short* __restrict__ x_bf,   // [N,256] bf16
    const unsigned short* __restrict__ wh_f,   // fragment-major bf16
    const float* __restrict__ ah,              // [8,128] f32
    unsigned short* __restrict__ h_bf,         // [N,512] bf16 out
    float* __restrict__ s1s, float* __restrict__ s1d, int N)
{
    __shared__ unsigned short Os[64][72];

    const int t = threadIdx.x;
    const int w = t >> 6, lane = t & 63;
    const int q = lane >> 4, m = lane & 15;
    const int n0 = blockIdx.x * 64;
    const int h0 = blockIdx.y * 4;

    int r = n0 + 16 * w + m;
    const unsigned short* xr = x_bf + (long)(r < N ? r : N - 1) * 256;
    short8 afrag[8];
    #pragma unroll
    for (int ks = 0; ks < 8; ++ks)
        afrag[ks] = *(const short8*)(xr + ks * 32 + q * 8);

    #pragma unroll
    for (int hi = 0; hi < 4; ++hi) {
        const int h = h0 + hi;
        f32x4 acc[4] = {};
        const unsigned short* Bh = wh_f + (((long)h * 32) << 9);
        #pragma unroll
        for (int ks = 0; ks < 8; ++ks) {
            #pragma unroll
            for (int c = 0; c < 4; ++c) {
                short8 b = *(const short8*)(Bh + (((ks * 4 + c) << 9) + lane * 8));
                acc[c] = __builtin_amdgcn_mfma_f32_16x16x32_bf16(afrag[ks], b, acc[c], 0, 0, 0);
            }
        }

        const float* a1 = ah + h * 128;
        float a1m = a1[m], a1m16 = a1[16 + m], a1m32 = a1[32 + m], a1m48 = a1[48 + m];
        float a2m = a1[64 + m], a2m16 = a1[80 + m], a2m32 = a1[96 + m], a2m48 = a1[112 + m];
        #pragma unroll
        for (int reg = 0; reg < 4; ++reg) {
            float p1 = acc[0][reg] * a1m + acc[1][reg] * a1m16 + acc[2][reg] * a1m32 + acc[3][reg] * a1m48;
            float p2 = acc[0][reg] * a2m + acc[1][reg] * a2m16 + acc[2][reg] * a2m32 + acc[3][reg] * a2m48;
            #pragma unroll
            for (int off = 1; off < 16; off <<= 1) {
                p1 += __shfl_xor(p1, off);
                p2 += __shfl_xor(p2, off);
            }
            int row = n0 + 16 * w + q * 4 + reg;
            if (m == 0 && row < N) {
                s1s[row * 8 + h] = p1;
                s1d[row * 8 + h] = p2;
            }
        }

        #pragma unroll
        for (int c = 0; c < 4; ++c)
            #pragma unroll
            for (int reg = 0; reg < 4; ++reg)
                Os[16 * w + q * 4 + reg][c * 16 + m] = f2bfu(acc[c][reg]);
        #pragma unroll
        for (int j = 0; j < 2; ++j) {
            int cc = j * 64 + lane;
            int row = cc >> 3, c8 = cc & 7;
            if (n0 + 16 * w + row < N)
                *(uint4*)(h_bf + (long)(n0 + 16 * w + row) * 512 + h * 64 + c8 * 8) =
                    *(const uint4*)&Os[16 * w + row][c8 * 8];
        }
    }
}

// ---------- layer-1 CSR gather v5: wave/node, inline ev, 4-edge unroll ----------
// Lane l: h = l>>3, holds uint4 (8 bf16) of the row. 4 edges in flight = 4 KB
// per wave-iteration on the L2-miss path (MLP is the binding constraint here).
__device__ __forceinline__ void acc8(float* acc, float ev, uint4 w) {
    acc[0] += ev * bfu2f((unsigned short)(w.x & 0xffffu));
    acc[1] += ev * bfu2f((unsigned short)(w.x >> 16));
    acc[2] += ev * bfu2f((unsigned short)(w.y & 0xffffu));
    acc[3] += ev * bfu2f((unsigned short)(w.y >> 16));
    acc[4] += ev * bfu2f((unsigned short)(w.z & 0xffffu));
    acc[5] += ev * bfu2f((unsigned short)(w.z >> 16));
    acc[6] += ev * bfu2f((unsigned short)(w.w & 0xffffu));
    acc[7] += ev * bfu2f((unsigned short)(w.w >> 16));
}

__global__ __launch_bounds__(256) void edge_agg1_kernel(
    const int* __restrict__ row_start, const int* __restrict__ csr_dst,
    const float* __restrict__ s1s, const float* __restrict__ s1d,
    const uint4* __restrict__ h_q,         // [N*64] uint4 (= [N,512] bf16)
    uint4* __restrict__ xcat_q,            // [N*64]
    int N)
{
    int lane = threadIdx.x & 63;
    int n = blockIdx.x * 4 + (threadIdx.x >> 6);
    if (n >= N) return;
    int h = lane >> 3;
    int beg = row_start[n], end = row_start[n + 1];
    float ss = s1s[n * 8 + h];

    float acc[8] = {0.f, 0.f, 0.f, 0.f, 0.f, 0.f, 0.f, 0.f};
    float rs = 0.f;
    int i = beg;
    for (; i + 4 <= end; i += 4) {
        int d0 = csr_dst[i], d1 = csr_dst[i + 1], d2 = csr_dst[i + 2], d3 = csr_dst[i + 3];
        float sd0 = s1d[d0 * 8 + h];
        float sd1 = s1d[d1 * 8 + h];
        float sd2 = s1d[d2 * 8 + h];
        float sd3 = s1d[d3 * 8 + h];
        uint4 w0 = h_q[(long)d0 * 64 + lane];
        uint4 w1 = h_q[(long)d1 * 64 + lane];
        uint4 w2 = h_q[(long)d2 * 64 + lane];
        uint4 w3 = h_q[(long)d3 * 64 + lane];
        float sc0 = ss + sd0, sc1 = ss + sd1, sc2 = ss + sd2, sc3 = ss + sd3;
        float lr0 = sc0 > 0.f ? sc0 : ALPHA * sc0;
        float lr1 = sc1 > 0.f ? sc1 : ALPHA * sc1;
        float lr2 = sc2 > 0.f ? sc2 : ALPHA * sc2;
        float lr3 = sc3 > 0.f ? sc3 : ALPHA * sc3;
        float ev0 = __expf(-lr0), ev1 = __expf(-lr1), ev2 = __expf(-lr2), ev3 = __expf(-lr3);
        rs += (ev0 + ev1) + (ev2 + ev3);
        acc8(acc, ev0, w0);
        acc8(acc, ev1, w1);
        acc8(acc, ev2, w2);
        acc8(acc, ev3, w3);
    }
    for (; i + 2 <= end; i += 2) {
        int d0 = csr_dst[i], d1 = csr_dst[i + 1];
        float sd0 = s1d[d0 * 8 + h];
        float sd1 = s1d[d1 * 8 + h];
        uint4 w0 = h_q[(long)d0 * 64 + lane];
        uint4 w1 = h_q[(long)d1 * 64 + lane];
        float sc0 = ss + sd0, sc1 = ss + sd1;
        float lr0 = sc0 > 0.f ? sc0 : ALPHA * sc0;
        float lr1 = sc1 > 0.f ? sc1 : ALPHA * sc1;
        float ev0 = __expf(-lr0), ev1 = __expf(-lr1);
        rs += ev0 + ev1;
        acc8(acc, ev0, w0);
        acc8(acc, ev1, w1);
    }
    if (i < end) {
        int d = csr_dst[i];
        float sd = s1d[d * 8 + h];
        uint4 wv = h_q[(long)d * 64 + lane];
        float sc = ss + sd;
        float lr = sc > 0.f ? sc : ALPHA * sc;
        float ev = __expf(-lr);
        rs += ev;
        acc8(acc, ev, wv);
    }
    float inv = 1.f / rs;
    unsigned short o[8];
    #pragma unroll
    for (int j = 0; j < 8; ++j) {
        float v = acc[j] * inv;
        v = v > 0.f ? v : __expf(v) - 1.f;   // elu
        o[j] = f2bfu(v);
    }
    xcat_q[(long)n * 64 + lane] = *(const uint4*)o;
}

// ---------- layer-2 GEMM + fused attn2: 2 threads per node (split-k) ----------
__global__ __launch_bounds__(256) void gemm2_kernel(
    const unsigned short* __restrict__ xcat_bf, // [N,512] bf16
    const float* __restrict__ Wo,               // [512,10] f32
    const float* __restrict__ ao,               // [20] f32
    float* __restrict__ h2p,                    // [N,16] f32, pad=0
    float* __restrict__ s2s, float* __restrict__ s2d, int N)
{
    int tid = blockIdx.x * 256 + threadIdx.x;
    int n = tid >> 1;
    if (n >= N) return;
    int half = tid & 1;
    float acc[NC];
    #pragma unroll
    for (int c = 0; c < NC; ++c) acc[c] = 0.f;
    const uint4* xp = (const uint4*)(xcat_bf + (long)n * 512) + half * 32;
    for (int k8 = 0; k8 < 32; ++k8) {
        uint4 w = xp[k8];
        float f[8];
        f[0] = bfu2f((unsigned short)(w.x & 0xffffu)); f[1] = bfu2f((unsigned short)(w.x >> 16));
        f[2] = bfu2f((unsigned short)(w.y & 0xffffu)); f[3] = bfu2f((unsigned short)(w.y >> 16));
        f[4] = bfu2f((unsigned short)(w.z & 0xffffu)); f[5] = bfu2f((unsigned short)(w.z >> 16));
        f[6] = bfu2f((unsigned short)(w.w & 0xffffu)); f[7] = bfu2f((unsigned short)(w.w >> 16));
        #pragma unroll
        for (int u = 0; u < 8; ++u) {
            const float* wr = Wo + ((half * 32 + k8) * 8 + u) * NC;
            #pragma unroll
            for (int c = 0; c < NC; ++c) acc[c] += f[u] * wr[c];
        }
    }
    #pragma unroll
    for (int c = 0; c < NC; ++c) acc[c] += __shfl_xor(acc[c], 1, 64);
    if (half == 0) {
        float s1 = 0.f, s2 = 0.f;
        *(float4*)(h2p + (long)n * 16)      = make_float4(acc[0], acc[1], acc[2], acc[3]);
        *(float4*)(h2p + (long)n * 16 + 4)  = make_float4(acc[4], acc[5], acc[6], acc[7]);
        *(float4*)(h2p + (long)n * 16 + 8)  = make_float4(acc[8], acc[9], 0.f, 0.f);
        *(float4*)(h2p + (long)n * 16 + 12) = make_float4(0.f, 0.f, 0.f, 0.f);
        #pragma unroll
        for (int c = 0; c < NC; ++c) {
            s1 += acc[c] * ao[c];
            s2 += acc[c] * ao[NC + c];
        }
        s2s[n] = s1;
        s2d[n] = s2;
    }
}

// ---------- layer-2 CSR gather v2: wave/node, 8 edge slots x 8 dim-lanes ----------
// Lane = (j = lane>>3 edge slot, c2 = lane&7 covering classes 2c2,2c2+1 via float2).
// 8 edges in flight per iteration (2x the MLP of the 4-slot version).
__global__ __launch_bounds__(256) void edge_agg2_kernel(
    const int* __restrict__ row_start, const int* __restrict__ csr_dst,
    const float* __restrict__ h2p,             // [N,16] f32, pad=0
    const float* __restrict__ s_src2, const float* __restrict__ s_dst2,
    void* __restrict__ out, const void* __restrict__ x_raw, int N)
{
    bool isf32 = detect_f32(x_raw);   // all lanes active
    int lane = threadIdx.x & 63;
    int n = blockIdx.x * 4 + (threadIdx.x >> 6);
    if (n >= N) return;
    int c2 = lane & 7, j = lane >> 3;   // 8 edge slots x 8 class-pairs
    int beg = row_start[n], end = row_start[n + 1];
    float ss = s_src2[n];
    float rs = 0.f, a0 = 0.f, a1 = 0.f;
    for (int i0 = beg; i0 < end; i0 += 8) {
        int i = i0 + j;
        if (i < end) {
            int d = csr_dst[i];
            float sc = ss + s_dst2[d];
            float lr = sc > 0.f ? sc : ALPHA * sc;
            float ev = __expf(-lr);
            rs += ev;
            float2 hv = *(const float2*)(h2p + (long)d * 16 + c2 * 2);
            a0 += ev * hv.x;
            a1 += ev * hv.y;
        }
    }
    rs += __shfl_xor(rs, 8);  rs += __shfl_xor(rs, 16);  rs += __shfl_xor(rs, 32);
    a0 += __shfl_xor(a0, 8);  a0 += __shfl_xor(a0, 16);  a0 += __shfl_xor(a0, 32);
    a1 += __shfl_xor(a1, 8);  a1 += __shfl_xor(a1, 16);  a1 += __shfl_xor(a1, 32);
    float inv = 1.f / rs;
    float v0 = a0 * inv, v1 = a1 * inv;
    v0 = v0 > 0.f ? v0 : __expf(v0) - 1.f;       // elu
    v1 = v1 > 0.f ? v1 : __expf(v1) - 1.f;
    // log-softmax over the 10 valid classes (c2<5 holds valid pairs)
    bool valid = (c2 * 2 + 1 < NC);
    float vm = valid ? fmaxf(v0, v1) : -1e30f;
    #pragma unroll
    for (int off = 1; off < 8; off <<= 1) vm = fmaxf(vm, __shfl_xor(vm, off, 64));
    float ex = valid ? (__expf(v0 - vm) + __expf(v1 - vm)) : 0.f;
    #pragma unroll
    for (int off = 1; off < 8; off <<= 1) ex += __shfl_xor(ex, off, 64);
    float lse = vm + logf(ex);
    if (valid && j == 0) {
        if (isf32) {
            *(float2*)((float*)out + (long)n * NC + c2 * 2) = make_float2(v0 - lse, v1 - lse);
        } else {
            unsigned int o = (unsigned int)f2bfu(v0 - lse) | ((unsigned int)f2bfu(v1 - lse) << 16);
            *(unsigned int*)((unsigned short*)out + (long)n * NC + c2 * 2) = o;
        }
    }
}

extern "C" void kernel_launch(void* const* d_in, const int* in_sizes, int n_in,
                              void* d_out, int out_size, void* d_ws, size_t ws_size,
                              hipStream_t stream)
{
    const void* x_raw  = d_in[0];
    const int*  esrc   = (const int*)d_in[1];
    const int*  edst   = (const int*)d_in[2];
    const void* Wh_raw = d_in[3];
    const void* ah_raw = d_in[4];
    const void* Wo_raw = d_in[5];
    const void* ao_raw = d_in[6];

    const int N = in_sizes[0] / F_IN;
    const int E = in_sizes[1];

    char* ws = (char*)d_ws;
    size_t off = 0;
    auto alloc = [&](size_t bytes) -> void* {
        void* p = ws + off;
        off = (off + bytes + 255) & ~(size_t)255;
        return p;
    };
    // zero-init region first (counts|cursor contiguous -> ONE memset)
    int*            counts    = (int*)           alloc((size_t)N * 4);
    int*            cursor    = (int*)           alloc((size_t)N * 4);
    size_t clear_span = (size_t)((char*)cursor + (size_t)N * 4 - (char*)counts);

    unsigned short* x_bf      = (unsigned short*)alloc((size_t)N * F_IN * 2);
    unsigned short* wh_f      = (unsigned short*)alloc((size_t)H_HEADS * D_HID * F_IN * 2);
    float*          ah32      = (float*)         alloc((size_t)H_HEADS * 2 * D_HID * 4);
    float*          Wo32      = (float*)         alloc((size_t)512 * NC * 4);
    float*          ao32      = (float*)         alloc((size_t)2 * NC * 4);
    unsigned short* h_bf      = (unsigned short*)alloc((size_t)N * 512 * 2);
    unsigned short* xcat_bf   = (unsigned short*)alloc((size_t)N * 512 * 2);
    float*          s1s       = (float*)         alloc((size_t)N * 8 * 4);
    float*          s1d       = (float*)         alloc((size_t)N * 8 * 4);
    float*          h2p       = (float*)         alloc((size_t)N * 16 * 4);
    float*          s2s       = (float*)         alloc((size_t)N * 4);
    float*          s2d       = (float*)         alloc((size_t)N * 4);
    int*            row_start = (int*)           alloc((size_t)(N + 1) * 4);
    int*            csr_dst   = (int*)           alloc((size_t)E * 4);
    (void)ws_size;

    hipMemsetAsync(counts, 0, clear_span, stream);

    // fused converts + histogram (dtype detected per-block from x sample)
    int bx = (int)(((long)N * F_IN / 8 + 255) / 256);      // x blocks
    int bw = bx + (H_HEADS * F_IN * D_HID) / 256;          // + W frag blocks
    int ba = bw + (H_HEADS * 2 * D_HID) / 256;             // + ah blocks
    int bo = ba + (512 * NC) / 256;                        // + Wo blocks; bo = ao block
    int nb = bo + 1 + (E + 255) / 256;                     // + hist blocks
    prep_kernel<<<nb, 256, 0, stream>>>(x_raw, x_bf, Wh_raw, wh_f, ah_raw, ah32,
                                        Wo_raw, Wo32, ao_raw, ao32,
                                        esrc, counts, N, E, bx, bw, ba, bo);
    scan_kernel<<<1, SCAN_T, 0, stream>>>(counts, row_start, N, E);
    scatter_kernel<<<(E + 255) / 256, 256, 0, stream>>>(esrc, edst, row_start, cursor, csr_dst, E);

    // layer 1
    dim3 g1((N + 63) / 64, H_HEADS / 4);
    gemm1_kernel<<<g1, 256, 0, stream>>>(x_bf, wh_f, ah32, h_bf, s1s, s1d, N);
    edge_agg1_kernel<<<(N + 3) / 4, 256, 0, stream>>>(row_start, csr_dst, s1s, s1d,
                                                      (const uint4*)h_bf, (uint4*)xcat_bf, N);

    // layer 2
    gemm2_kernel<<<(2 * N + 255) / 256, 256, 0, stream>>>(xcat_bf, Wo32, ao32, h2p, s2s, s2d, N);
    edge_agg2_kernel<<<(N + 3) / 4, 256, 0, stream>>>(row_start, csr_dst, h2p, s2s, s2d, d_out, x_raw, N);
}

// Round 3
// 484.845 us; speedup vs baseline: 2.1021x; 1.1111x over previous
//
#include <hip/hip_runtime.h>
#include <hip/hip_bf16.h>

#define F_IN    256
#define D_HID   64
#define H_HEADS 8
#define NC      10
#define ALPHA   0.2f
#define SCAN_T  1024

typedef __attribute__((ext_vector_type(8))) short short8;
typedef __attribute__((ext_vector_type(4))) float f32x4;

// ---------- bf16 helpers ----------
__device__ __forceinline__ float bfu2f(unsigned short u) {
    union { float f; unsigned int i; } c; c.i = ((unsigned int)u) << 16; return c.f;
}
__device__ __forceinline__ unsigned short f2bfu(float f) {
    union { float f; unsigned int i; } c; c.f = f;
    unsigned int x = c.i;
    x += 0x7fffu + ((x >> 16) & 1u);   // round-to-nearest-even
    return (unsigned short)(x >> 16);
}

// ---------- inline dtype detection (f32 vs bf16 storage), wave-uniform ----------
// MUST run with ALL 64 lanes active (__ballot counts active lanes only).
__device__ __forceinline__ bool detect_f32(const void* xraw) {
    unsigned int w = ((const unsigned int*)xraw)[threadIdx.x & 63];
    unsigned int e = (w >> 7) & 0xffu;
    unsigned long long m = __ballot(e >= 140u);
    return __popcll(m) > 8;
}

// ---------- fused prep: all input conversions + edge histogram ----------
__global__ __launch_bounds__(256) void prep_kernel(
    const void* __restrict__ x_raw,  unsigned short* __restrict__ x_bf,
    const void* __restrict__ Wh_raw, unsigned short* __restrict__ wh_f,
    const void* __restrict__ ah_raw, float* __restrict__ ah32,
    const void* __restrict__ Wo_raw, float* __restrict__ Wo32,
    const void* __restrict__ ao_raw, float* __restrict__ ao32,
    const int* __restrict__ esrc, int* __restrict__ counts,
    int N, int E, int bx, int bw, int ba, int bo)
{
    int b = blockIdx.x;
    bool isf32 = detect_f32(x_raw);   // all lanes active here
    if (b < bx) {                       // x -> bf16, 8 elems/thread
        long i = (long)b * 256 + threadIdx.x;
        long n8 = (long)N * F_IN / 8;
        if (i < n8) {
            unsigned short o[8];
            if (isf32) {
                const float4* s = (const float4*)x_raw + i * 2;
                float4 a = s[0], bb = s[1];
                o[0] = f2bfu(a.x);  o[1] = f2bfu(a.y);
                o[2] = f2bfu(a.z);  o[3] = f2bfu(a.w);
                o[4] = f2bfu(bb.x); o[5] = f2bfu(bb.y);
                o[6] = f2bfu(bb.z); o[7] = f2bfu(bb.w);
            } else {
                *(uint4*)o = ((const uint4*)x_raw)[i];
            }
            *(uint4*)(x_bf + i * 8) = *(uint4*)o;
        }
    } else if (b < bw) {                // W_heads [8][256][64] -> fragment-major bf16
        int i = (b - bx) * 256 + threadIdx.x;
        int d = i & 63, k = (i >> 6) & 255, h = i >> 14;
        float v = isf32 ? ((const float*)Wh_raw)[i] : bfu2f(((const unsigned short*)Wh_raw)[i]);
        int ks = k >> 5, q = (k >> 3) & 3, j = k & 7;
        int c = d >> 4, m = d & 15;
        wh_f[(((h * 8 + ks) * 4 + c) << 9) + (q * 16 + m) * 8 + j] = f2bfu(v);
    } else if (b < ba) {                // a_heads -> f32 (1024)
        int i = (b - bw) * 256 + threadIdx.x;
        ah32[i] = isf32 ? ((const float*)ah_raw)[i] : bfu2f(((const unsigned short*)ah_raw)[i]);
    } else if (b < bo) {                // W_out -> f32 (5120)
        int i = (b - ba) * 256 + threadIdx.x;
        Wo32[i] = isf32 ? ((const float*)Wo_raw)[i] : bfu2f(((const unsigned short*)Wo_raw)[i]);
    } else if (b == bo) {               // a_out -> f32 (20)
        int i = threadIdx.x;
        if (i < 2 * NC)
            ao32[i] = isf32 ? ((const float*)ao_raw)[i] : bfu2f(((const unsigned short*)ao_raw)[i]);
    } else {                            // edge histogram
        int e = (b - bo - 1) * 256 + threadIdx.x;
        if (e < E) atomicAdd(&counts[esrc[e]], 1);
    }
}

// ---------- CSR scan ----------
__global__ __launch_bounds__(SCAN_T) void scan_kernel(
    const int* __restrict__ counts, int* __restrict__ row_start, int N, int E)
{
    __shared__ int sums[SCAN_T];
    int t = threadIdx.x;
    int chunk = (N + SCAN_T - 1) / SCAN_T;
    int b = t * chunk, e = min(b + chunk, N);
    int s = 0;
    for (int i = b; i < e; ++i) s += counts[i];
    sums[t] = s;
    __syncthreads();
    for (int off = 1; off < SCAN_T; off <<= 1) {
        int u = (t >= off) ? sums[t - off] : 0;
        __syncthreads();
        sums[t] += u;
        __syncthreads();
    }
    int running = sums[t] - s;
    for (int i = b; i < e; ++i) { row_start[i] = running; running += counts[i]; }
    if (t == SCAN_T - 1) row_start[N] = E;
}

// ---------- lean CSR scatter: coalesced reads, one atomic, one 4B scatter ----------
__global__ __launch_bounds__(256) void scatter_kernel(
    const int* __restrict__ src, const int* __restrict__ dst,
    const int* __restrict__ row_start, int* __restrict__ cursor,
    int* __restrict__ csr_dst, int E)
{
    int e = blockIdx.x * 256 + threadIdx.x;
    if (e >= E) return;
    int s = src[e];
    int pos = atomicAdd(&cursor[s], 1);
    csr_dst[row_start[s] + pos] = dst[e];
}

// ---------- layer-1 MFMA GEMM + fused attn1 (fragment-major B, 8 heads/block) ----------
__global__ __launch_bounds__(256) void gemm1_kernel(
    const unsigned short* __restrict__ x_bf,   // [N,256] bf16
    const unsigned short* __restrict__ wh_f,   // fragment-major bf16
    const float* __restrict__ ah,              // [8,128] f32
    unsigned short* __restrict__ h_bf,         // [N,512] bf16 out
    float* __restrict__ s1s, float* __restrict__ s1d, int N)
{
    __shared__ unsigned short Os[64][72];

    const int t = threadIdx.x;
    const int w = t >> 6, lane = t & 63;
    const int q = lane >> 4, m = lane & 15;
    const int n0 = blockIdx.x * 64;

    int r = n0 + 16 * w + m;
    const unsigned short* xr = x_bf + (long)(r < N ? r : N - 1) * 256;
    short8 afrag[8];
    #pragma unroll
    for (int ks = 0; ks < 8; ++ks)
        afrag[ks] = *(const short8*)(xr + ks * 32 + q * 8);

    #pragma unroll
    for (int h = 0; h < 8; ++h) {
        f32x4 acc[4] = {};
        const unsigned short* Bh = wh_f + (((long)h * 32) << 9);
        #pragma unroll
        for (int ks = 0; ks < 8; ++ks) {
            #pragma unroll
            for (int c = 0; c < 4; ++c) {
                short8 b = *(const short8*)(Bh + (((ks * 4 + c) << 9) + lane * 8));
                acc[c] = __builtin_amdgcn_mfma_f32_16x16x32_bf16(afrag[ks], b, acc[c], 0, 0, 0);
            }
        }

        const float* a1 = ah + h * 128;
        float a1m = a1[m], a1m16 = a1[16 + m], a1m32 = a1[32 + m], a1m48 = a1[48 + m];
        float a2m = a1[64 + m], a2m16 = a1[80 + m], a2m32 = a1[96 + m], a2m48 = a1[112 + m];
        #pragma unroll
        for (int reg = 0; reg < 4; ++reg) {
            float p1 = acc[0][reg] * a1m + acc[1][reg] * a1m16 + acc[2][reg] * a1m32 + acc[3][reg] * a1m48;
            float p2 = acc[0][reg] * a2m + acc[1][reg] * a2m16 + acc[2][reg] * a2m32 + acc[3][reg] * a2m48;
            #pragma unroll
            for (int off = 1; off < 16; off <<= 1) {
                p1 += __shfl_xor(p1, off);
                p2 += __shfl_xor(p2, off);
            }
            int row = n0 + 16 * w + q * 4 + reg;
            if (m == 0 && row < N) {
                s1s[row * 8 + h] = p1;
                s1d[row * 8 + h] = p2;
            }
        }

        #pragma unroll
        for (int c = 0; c < 4; ++c)
            #pragma unroll
            for (int reg = 0; reg < 4; ++reg)
                Os[16 * w + q * 4 + reg][c * 16 + m] = f2bfu(acc[c][reg]);
        #pragma unroll
        for (int j = 0; j < 2; ++j) {
            int cc = j * 64 + lane;
            int row = cc >> 3, c8 = cc & 7;
            if (n0 + 16 * w + row < N)
                *(uint4*)(h_bf + (long)(n0 + 16 * w + row) * 512 + h * 64 + c8 * 8) =
                    *(const uint4*)&Os[16 * w + row][c8 * 8];
        }
    }
}

// ---------- layer-1 CSR gather + FUSED layer-2 GEMM epilogue ----------
// Wave per node; lane l holds dims [8l, 8l+8) of the aggregated row.
// After the edge loop: elu, then rank-10 projection (Wo slice is 320 B
// contiguous per lane, L1-resident), 6-stage shuffle reduce, lane 0 writes
// h2p[16] + s2s/s2d. xcat is never materialized (saves 50 MB wr + 51 MB rd).
__device__ __forceinline__ void acc8(float* acc, float ev, uint4 w) {
    acc[0] += ev * bfu2f((unsigned short)(w.x & 0xffffu));
    acc[1] += ev * bfu2f((unsigned short)(w.x >> 16));
    acc[2] += ev * bfu2f((unsigned short)(w.y & 0xffffu));
    acc[3] += ev * bfu2f((unsigned short)(w.y >> 16));
    acc[4] += ev * bfu2f((unsigned short)(w.z & 0xffffu));
    acc[5] += ev * bfu2f((unsigned short)(w.z >> 16));
    acc[6] += ev * bfu2f((unsigned short)(w.w & 0xffffu));
    acc[7] += ev * bfu2f((unsigned short)(w.w >> 16));
}

__global__ __launch_bounds__(256) void edge_agg1_kernel(
    const int* __restrict__ row_start, const int* __restrict__ csr_dst,
    const float* __restrict__ s1s, const float* __restrict__ s1d,
    const uint4* __restrict__ h_q,         // [N*64] uint4 (= [N,512] bf16)
    const float* __restrict__ Wo,          // [512,10] f32
    const float* __restrict__ ao,          // [20] f32
    float* __restrict__ h2p,               // [N,16] f32, pad=0
    float* __restrict__ s2s, float* __restrict__ s2d,
    int N)
{
    int lane = threadIdx.x & 63;
    int n = blockIdx.x * 4 + (threadIdx.x >> 6);
    if (n >= N) return;
    int h = lane >> 3;
    int beg = row_start[n], end = row_start[n + 1];
    float ss = s1s[n * 8 + h];

    float acc[8] = {0.f, 0.f, 0.f, 0.f, 0.f, 0.f, 0.f, 0.f};
    float rs = 0.f;
    int i = beg;
    for (; i + 4 <= end; i += 4) {
        int d0 = csr_dst[i], d1 = csr_dst[i + 1], d2 = csr_dst[i + 2], d3 = csr_dst[i + 3];
        float sd0 = s1d[d0 * 8 + h];
        float sd1 = s1d[d1 * 8 + h];
        float sd2 = s1d[d2 * 8 + h];
        float sd3 = s1d[d3 * 8 + h];
        uint4 w0 = h_q[(long)d0 * 64 + lane];
        uint4 w1 = h_q[(long)d1 * 64 + lane];
        uint4 w2 = h_q[(long)d2 * 64 + lane];
        uint4 w3 = h_q[(long)d3 * 64 + lane];
        float sc0 = ss + sd0, sc1 = ss + sd1, sc2 = ss + sd2, sc3 = ss + sd3;
        float lr0 = sc0 > 0.f ? sc0 : ALPHA * sc0;
        float lr1 = sc1 > 0.f ? sc1 : ALPHA * sc1;
        float lr2 = sc2 > 0.f ? sc2 : ALPHA * sc2;
        float lr3 = sc3 > 0.f ? sc3 : ALPHA * sc3;
        float ev0 = __expf(-lr0), ev1 = __expf(-lr1), ev2 = __expf(-lr2), ev3 = __expf(-lr3);
        rs += (ev0 + ev1) + (ev2 + ev3);
        acc8(acc, ev0, w0);
        acc8(acc, ev1, w1);
        acc8(acc, ev2, w2);
        acc8(acc, ev3, w3);
    }
    for (; i + 2 <= end; i += 2) {
        int d0 = csr_dst[i], d1 = csr_dst[i + 1];
        float sd0 = s1d[d0 * 8 + h];
        float sd1 = s1d[d1 * 8 + h];
        uint4 w0 = h_q[(long)d0 * 64 + lane];
        uint4 w1 = h_q[(long)d1 * 64 + lane];
        float sc0 = ss + sd0, sc1 = ss + sd1;
        float lr0 = sc0 > 0.f ? sc0 : ALPHA * sc0;
        float lr1 = sc1 > 0.f ? sc1 : ALPHA * sc1;
        float ev0 = __expf(-lr0), ev1 = __expf(-lr1);
        rs += ev0 + ev1;
        acc8(acc, ev0, w0);
        acc8(acc, ev1, w1);
    }
    if (i < end) {
        int d = csr_dst[i];
        float sd = s1d[d * 8 + h];
        uint4 wv = h_q[(long)d * 64 + lane];
        float sc = ss + sd;
        float lr = sc > 0.f ? sc : ALPHA * sc;
        float ev = __expf(-lr);
        rs += ev;
        acc8(acc, ev, wv);
    }
    float inv = 1.f / rs;
    float v[8];
    #pragma unroll
    for (int j = 0; j < 8; ++j) {
        float t2 = acc[j] * inv;
        v[j] = t2 > 0.f ? t2 : __expf(t2) - 1.f;   // elu -> xcat element (f32)
    }

    // fused layer-2 projection: p[c] = sum over this lane's 8 dims, then wave-reduce
    float p[NC];
    #pragma unroll
    for (int c = 0; c < NC; ++c) p[c] = 0.f;
    const float* WoL = Wo + lane * 80;     // rows 8*lane .. 8*lane+7, 10 f32 each
    #pragma unroll
    for (int u = 0; u < 8; ++u) {
        #pragma unroll
        for (int c5 = 0; c5 < 5; ++c5) {
            float2 wv2 = *(const float2*)(WoL + u * 10 + c5 * 2);
            p[c5 * 2]     += v[u] * wv2.x;
            p[c5 * 2 + 1] += v[u] * wv2.y;
        }
    }
    #pragma unroll
    for (int off = 1; off < 64; off <<= 1) {
        #pragma unroll
        for (int c = 0; c < NC; ++c) p[c] += __shfl_xor(p[c], off);
    }
    if (lane == 0) {
        *(float4*)(h2p + (long)n * 16)      = make_float4(p[0], p[1], p[2], p[3]);
        *(float4*)(h2p + (long)n * 16 + 4)  = make_float4(p[4], p[5], p[6], p[7]);
        *(float4*)(h2p + (long)n * 16 + 8)  = make_float4(p[8], p[9], 0.f, 0.f);
        *(float4*)(h2p + (long)n * 16 + 12) = make_float4(0.f, 0.f, 0.f, 0.f);
        float s1 = 0.f, s2 = 0.f;
        #pragma unroll
        for (int c = 0; c < NC; ++c) {
            s1 += p[c] * ao[c];
            s2 += p[c] * ao[NC + c];
        }
        s2s[n] = s1;
        s2d[n] = s2;
    }
}

// ---------- layer-2 CSR gather v2: wave/node, 8 edge slots x 8 dim-lanes ----------
// Lane = (j = lane>>3 edge slot, c2 = lane&7 covering classes 2c2,2c2+1 via float2).
__global__ __launch_bounds__(256) void edge_agg2_kernel(
    const int* __restrict__ row_start, const int* __restrict__ csr_dst,
    const float* __restrict__ h2p,             // [N,16] f32, pad=0
    const float* __restrict__ s_src2, const float* __restrict__ s_dst2,
    void* __restrict__ out, const void* __restrict__ x_raw, int N)
{
    bool isf32 = detect_f32(x_raw);   // all lanes active
    int lane = threadIdx.x & 63;
    int n = blockIdx.x * 4 + (threadIdx.x >> 6);
    if (n >= N) return;
    int c2 = lane & 7, j = lane >> 3;   // 8 edge slots x 8 class-pairs
    int beg = row_start[n], end = row_start[n + 1];
    float ss = s_src2[n];
    float rs = 0.f, a0 = 0.f, a1 = 0.f;
    for (int i0 = beg; i0 < end; i0 += 8) {
        int i = i0 + j;
        if (i < end) {
            int d = csr_dst[i];
            float sc = ss + s_dst2[d];
            float lr = sc > 0.f ? sc : ALPHA * sc;
            float ev = __expf(-lr);
            rs += ev;
            float2 hv = *(const float2*)(h2p + (long)d * 16 + c2 * 2);
            a0 += ev * hv.x;
            a1 += ev * hv.y;
        }
    }
    rs += __shfl_xor(rs, 8);  rs += __shfl_xor(rs, 16);  rs += __shfl_xor(rs, 32);
    a0 += __shfl_xor(a0, 8);  a0 += __shfl_xor(a0, 16);  a0 += __shfl_xor(a0, 32);
    a1 += __shfl_xor(a1, 8);  a1 += __shfl_xor(a1, 16);  a1 += __shfl_xor(a1, 32);
    float inv = 1.f / rs;
    float v0 = a0 * inv, v1 = a1 * inv;
    v0 = v0 > 0.f ? v0 : __expf(v0) - 1.f;       // elu
    v1 = v1 > 0.f ? v1 : __expf(v1) - 1.f;
    // log-softmax over the 10 valid classes (c2<5 holds valid pairs)
    bool valid = (c2 * 2 + 1 < NC);
    float vm = valid ? fmaxf(v0, v1) : -1e30f;
    #pragma unroll
    for (int off = 1; off < 8; off <<= 1) vm = fmaxf(vm, __shfl_xor(vm, off, 64));
    float ex = valid ? (__expf(v0 - vm) + __expf(v1 - vm)) : 0.f;
    #pragma unroll
    for (int off = 1; off < 8; off <<= 1) ex += __shfl_xor(ex, off, 64);
    float lse = vm + logf(ex);
    if (valid && j == 0) {
        if (isf32) {
            *(float2*)((float*)out + (long)n * NC + c2 * 2) = make_float2(v0 - lse, v1 - lse);
        } else {
            unsigned int o = (unsigned int)f2bfu(v0 - lse) | ((unsigned int)f2bfu(v1 - lse) << 16);
            *(unsigned int*)((unsigned short*)out + (long)n * NC + c2 * 2) = o;
        }
    }
}

extern "C" void kernel_launch(void* const* d_in, const int* in_sizes, int n_in,
                              void* d_out, int out_size, void* d_ws, size_t ws_size,
                              hipStream_t stream)
{
    const void* x_raw  = d_in[0];
    const int*  esrc   = (const int*)d_in[1];
    const int*  edst   = (const int*)d_in[2];
    const void* Wh_raw = d_in[3];
    const void* ah_raw = d_in[4];
    const void* Wo_raw = d_in[5];
    const void* ao_raw = d_in[6];

    const int N = in_sizes[0] / F_IN;
    const int E = in_sizes[1];

    char* ws = (char*)d_ws;
    size_t off = 0;
    auto alloc = [&](size_t bytes) -> void* {
        void* p = ws + off;
        off = (off + bytes + 255) & ~(size_t)255;
        return p;
    };
    // zero-init region first (counts|cursor contiguous -> ONE memset)
    int*            counts    = (int*)           alloc((size_t)N * 4);
    int*            cursor    = (int*)           alloc((size_t)N * 4);
    size_t clear_span = (size_t)((char*)cursor + (size_t)N * 4 - (char*)counts);

    unsigned short* x_bf      = (unsigned short*)alloc((size_t)N * F_IN * 2);
    unsigned short* wh_f      = (unsigned short*)alloc((size_t)H_HEADS * D_HID * F_IN * 2);
    float*          ah32      = (float*)         alloc((size_t)H_HEADS * 2 * D_HID * 4);
    float*          Wo32      = (float*)         alloc((size_t)512 * NC * 4);
    float*          ao32      = (float*)         alloc((size_t)2 * NC * 4);
    unsigned short* h_bf      = (unsigned short*)alloc((size_t)N * 512 * 2);
    float*          s1s       = (float*)         alloc((size_t)N * 8 * 4);
    float*          s1d       = (float*)         alloc((size_t)N * 8 * 4);
    float*          h2p       = (float*)         alloc((size_t)N * 16 * 4);
    float*          s2s       = (float*)         alloc((size_t)N * 4);
    float*          s2d       = (float*)         alloc((size_t)N * 4);
    int*            row_start = (int*)           alloc((size_t)(N + 1) * 4);
    int*            csr_dst   = (int*)           alloc((size_t)E * 4);
    (void)ws_size;

    hipMemsetAsync(counts, 0, clear_span, stream);

    // fused converts + histogram (dtype detected per-block from x sample)
    int bx = (int)(((long)N * F_IN / 8 + 255) / 256);      // x blocks
    int bw = bx + (H_HEADS * F_IN * D_HID) / 256;          // + W frag blocks
    int ba = bw + (H_HEADS * 2 * D_HID) / 256;             // + ah blocks
    int bo = ba + (512 * NC) / 256;                        // + Wo blocks; bo = ao block
    int nb = bo + 1 + (E + 255) / 256;                     // + hist blocks
    prep_kernel<<<nb, 256, 0, stream>>>(x_raw, x_bf, Wh_raw, wh_f, ah_raw, ah32,
                                        Wo_raw, Wo32, ao_raw, ao32,
                                        esrc, counts, N, E, bx, bw, ba, bo);
    scan_kernel<<<1, SCAN_T, 0, stream>>>(counts, row_start, N, E);
    scatter_kernel<<<(E + 255) / 256, 256, 0, stream>>>(esrc, edst, row_start, cursor, csr_dst, E);

    // layer 1 (gemm) -> layer-1 aggregation with fused layer-2 projection
    gemm1_kernel<<<(N + 63) / 64, 256, 0, stream>>>(x_bf, wh_f, ah32, h_bf, s1s, s1d, N);
    edge_agg1_kernel<<<(N + 3) / 4, 256, 0, stream>>>(row_start, csr_dst, s1s, s1d,
                                                      (const uint4*)h_bf, Wo32, ao32,
                                                      h2p, s2s, s2d, N);

    // layer-2 aggregation + log-softmax
    edge_agg2_kernel<<<(N + 3) / 4, 256, 0, stream>>>(row_start, csr_dst, h2p, s2s, s2d, d_out, x_raw, N);
}

// Round 4
// 439.086 us; speedup vs baseline: 2.3212x; 1.1042x over previous
//
#include <hip/hip_runtime.h>
#include <hip/hip_bf16.h>

#define F_IN    256
#define D_HID   64
#define H_HEADS 8
#define NC      10
#define ALPHA   0.2f
#define SCAN_T  1024

typedef __attribute__((ext_vector_type(8))) short short8;
typedef __attribute__((ext_vector_type(4))) float f32x4;

// ---------- bf16 helpers ----------
__device__ __forceinline__ float bfu2f(unsigned short u) {
    union { float f; unsigned int i; } c; c.i = ((unsigned int)u) << 16; return c.f;
}
__device__ __forceinline__ unsigned short f2bfu(float f) {
    union { float f; unsigned int i; } c; c.f = f;
    unsigned int x = c.i;
    x += 0x7fffu + ((x >> 16) & 1u);   // round-to-nearest-even
    return (unsigned short)(x >> 16);
}

// ---------- inline dtype detection (f32 vs bf16 storage), wave-uniform ----------
// MUST run with ALL 64 lanes active (__ballot counts active lanes only).
__device__ __forceinline__ bool detect_f32(const void* xraw) {
    unsigned int w = ((const unsigned int*)xraw)[threadIdx.x & 63];
    unsigned int e = (w >> 7) & 0xffu;
    unsigned long long m = __ballot(e >= 140u);
    return __popcll(m) > 8;
}

// ---------- fused prep: all input conversions + edge histogram (+pos stash) ----------
__global__ __launch_bounds__(256) void prep_kernel(
    const void* __restrict__ x_raw,  unsigned short* __restrict__ x_bf,
    const void* __restrict__ Wh_raw, unsigned short* __restrict__ wh_f,
    const void* __restrict__ ah_raw, float* __restrict__ ah32,
    const void* __restrict__ Wo_raw, unsigned short* __restrict__ wob_f,
    const void* __restrict__ ao_raw, float* __restrict__ ao32,
    const int* __restrict__ esrc, int* __restrict__ counts, int* __restrict__ pos_e,
    int N, int E, int bx, int bw, int ba, int bo)
{
    int b = blockIdx.x;
    bool isf32 = detect_f32(x_raw);   // all lanes active here
    if (b < bx) {                       // x -> bf16, 8 elems/thread
        long i = (long)b * 256 + threadIdx.x;
        long n8 = (long)N * F_IN / 8;
        if (i < n8) {
            unsigned short o[8];
            if (isf32) {
                const float4* s = (const float4*)x_raw + i * 2;
                float4 a = s[0], bb = s[1];
                o[0] = f2bfu(a.x);  o[1] = f2bfu(a.y);
                o[2] = f2bfu(a.z);  o[3] = f2bfu(a.w);
                o[4] = f2bfu(bb.x); o[5] = f2bfu(bb.y);
                o[6] = f2bfu(bb.z); o[7] = f2bfu(bb.w);
            } else {
                *(uint4*)o = ((const uint4*)x_raw)[i];
            }
            *(uint4*)(x_bf + i * 8) = *(uint4*)o;
        }
    } else if (b < bw) {                // W_heads [8][256][64] -> fragment-major bf16
        int i = (b - bx) * 256 + threadIdx.x;
        int d = i & 63, k = (i >> 6) & 255, h = i >> 14;
        float v = isf32 ? ((const float*)Wh_raw)[i] : bfu2f(((const unsigned short*)Wh_raw)[i]);
        int ks = k >> 5, q = (k >> 3) & 3, j = k & 7;
        int c = d >> 4, m = d & 15;
        wh_f[(((h * 8 + ks) * 4 + c) << 9) + (q * 16 + m) * 8 + j] = f2bfu(v);
    } else if (b < ba) {                // a_heads -> f32 (1024)
        int i = (b - bw) * 256 + threadIdx.x;
        ah32[i] = isf32 ? ((const float*)ah_raw)[i] : bfu2f(((const unsigned short*)ah_raw)[i]);
    } else if (b < bo) {                // W_out [512,10] -> fragment-major bf16, cols padded to 16
        int i = (b - ba) * 256 + threadIdx.x;   // 0..8191 = (ks<<9) + L*8 + j
        int j = i & 7, L = (i >> 3) & 63, ks = i >> 9;
        int q = L >> 4, m = L & 15;
        int k = ks * 32 + q * 8 + j;
        float v = 0.f;
        if (m < NC)
            v = isf32 ? ((const float*)Wo_raw)[k * NC + m] : bfu2f(((const unsigned short*)Wo_raw)[k * NC + m]);
        wob_f[i] = f2bfu(v);
    } else if (b == bo) {               // a_out -> f32 (20)
        int i = threadIdx.x;
        if (i < 2 * NC)
            ao32[i] = isf32 ? ((const float*)ao_raw)[i] : bfu2f(((const unsigned short*)ao_raw)[i]);
    } else {                            // edge histogram + stash row-local position
        int e = (b - bo - 1) * 256 + threadIdx.x;
        if (e < E) {
            int s = esrc[e];
            int pos = atomicAdd(&counts[s], 1);
            pos_e[e] = pos;
        }
    }
}

// ---------- CSR scan ----------
__global__ __launch_bounds__(SCAN_T) void scan_kernel(
    const int* __restrict__ counts, int* __restrict__ row_start, int N, int E)
{
    __shared__ int sums[SCAN_T];
    int t = threadIdx.x;
    int chunk = (N + SCAN_T - 1) / SCAN_T;
    int b = t * chunk, e = min(b + chunk, N);
    int s = 0;
    for (int i = b; i < e; ++i) s += counts[i];
    sums[t] = s;
    __syncthreads();
    for (int off = 1; off < SCAN_T; off <<= 1) {
        int u = (t >= off) ? sums[t - off] : 0;
        __syncthreads();
        sums[t] += u;
        __syncthreads();
    }
    int running = sums[t] - s;
    for (int i = b; i < e; ++i) { row_start[i] = running; running += counts[i]; }
    if (t == SCAN_T - 1) row_start[N] = E;
}

// ---------- CSR scatter: no atomics (positions stashed by prep) ----------
__global__ __launch_bounds__(256) void scatter_kernel(
    const int* __restrict__ src, const int* __restrict__ dst,
    const int* __restrict__ row_start, const int* __restrict__ pos_e,
    int* __restrict__ csr_dst, int E)
{
    int e = blockIdx.x * 256 + threadIdx.x;
    if (e >= E) return;
    int s = src[e];
    csr_dst[row_start[s] + pos_e[e]] = dst[e];
}

// ---------- layer-1 MFMA GEMM + fused attn1 (fragment-major B, 8 heads/block) ----------
__global__ __launch_bounds__(256) void gemm1_kernel(
    const unsigned short* __restrict__ x_bf,   // [N,256] bf16
    const unsigned short* __restrict__ wh_f,   // fragment-major bf16
    const float* __restrict__ ah,              // [8,128] f32
    unsigned short* __restrict__ h_bf,         // [N,512] bf16 out
    float* __restrict__ s1s, float* __restrict__ s1d, int N)
{
    __shared__ unsigned short Os[64][72];

    const int t = threadIdx.x;
    const int w = t >> 6, lane = t & 63;
    const int q = lane >> 4, m = lane & 15;
    const int n0 = blockIdx.x * 64;

    int r = n0 + 16 * w + m;
    const unsigned short* xr = x_bf + (long)(r < N ? r : N - 1) * 256;
    short8 afrag[8];
    #pragma unroll
    for (int ks = 0; ks < 8; ++ks)
        afrag[ks] = *(const short8*)(xr + ks * 32 + q * 8);

    #pragma unroll
    for (int h = 0; h < 8; ++h) {
        f32x4 acc[4] = {};
        const unsigned short* Bh = wh_f + (((long)h * 32) << 9);
        #pragma unroll
        for (int ks = 0; ks < 8; ++ks) {
            #pragma unroll
            for (int c = 0; c < 4; ++c) {
                short8 b = *(const short8*)(Bh + (((ks * 4 + c) << 9) + lane * 8));
                acc[c] = __builtin_amdgcn_mfma_f32_16x16x32_bf16(afrag[ks], b, acc[c], 0, 0, 0);
            }
        }

        const float* a1 = ah + h * 128;
        float a1m = a1[m], a1m16 = a1[16 + m], a1m32 = a1[32 + m], a1m48 = a1[48 + m];
        float a2m = a1[64 + m], a2m16 = a1[80 + m], a2m32 = a1[96 + m], a2m48 = a1[112 + m];
        #pragma unroll
        for (int reg = 0; reg < 4; ++reg) {
            float p1 = acc[0][reg] * a1m + acc[1][reg] * a1m16 + acc[2][reg] * a1m32 + acc[3][reg] * a1m48;
            float p2 = acc[0][reg] * a2m + acc[1][reg] * a2m16 + acc[2][reg] * a2m32 + acc[3][reg] * a2m48;
            #pragma unroll
            for (int off = 1; off < 16; off <<= 1) {
                p1 += __shfl_xor(p1, off);
                p2 += __shfl_xor(p2, off);
            }
            int row = n0 + 16 * w + q * 4 + reg;
            if (m == 0 && row < N) {
                s1s[row * 8 + h] = p1;
                s1d[row * 8 + h] = p2;
            }
        }

        #pragma unroll
        for (int c = 0; c < 4; ++c)
            #pragma unroll
            for (int reg = 0; reg < 4; ++reg)
                Os[16 * w + q * 4 + reg][c * 16 + m] = f2bfu(acc[c][reg]);
        #pragma unroll
        for (int j = 0; j < 2; ++j) {
            int cc = j * 64 + lane;
            int row = cc >> 3, c8 = cc & 7;
            if (n0 + 16 * w + row < N)
                *(uint4*)(h_bf + (long)(n0 + 16 * w + row) * 512 + h * 64 + c8 * 8) =
                    *(const uint4*)&Os[16 * w + row][c8 * 8];
        }
    }
}

// ---------- layer-1 CSR gather + MFMA-batched layer-2 projection ----------
// Block = 4 waves x 4 nodes each (16 nodes). Gather loop identical to the
// proven r2 structure (4-edge unroll, ~3.8 TB/s fill). Aggregated rows go to
// LDS as bf16 [16][512+8]; after one barrier, wave 0 computes the 16x16
// class projection with 16 MFMAs (Wo pre-swizzled frag-major, cols padded 0).
__device__ __forceinline__ void acc8(float* acc, float ev, uint4 w) {
    acc[0] += ev * bfu2f((unsigned short)(w.x & 0xffffu));
    acc[1] += ev * bfu2f((unsigned short)(w.x >> 16));
    acc[2] += ev * bfu2f((unsigned short)(w.y & 0xffffu));
    acc[3] += ev * bfu2f((unsigned short)(w.y >> 16));
    acc[4] += ev * bfu2f((unsigned short)(w.z & 0xffffu));
    acc[5] += ev * bfu2f((unsigned short)(w.z >> 16));
    acc[6] += ev * bfu2f((unsigned short)(w.w & 0xffffu));
    acc[7] += ev * bfu2f((unsigned short)(w.w >> 16));
}

__global__ __launch_bounds__(256) void edge_agg1_kernel(
    const int* __restrict__ row_start, const int* __restrict__ csr_dst,
    const float* __restrict__ s1s, const float* __restrict__ s1d,
    const uint4* __restrict__ h_q,             // [N*64] uint4 (= [N,512] bf16)
    const unsigned short* __restrict__ wob,    // [16][64][8] bf16 frag-major (Wo)
    const float* __restrict__ ao,              // [20] f32
    float* __restrict__ h2p,                   // [N,16] f32, pad=0
    float* __restrict__ s2s, float* __restrict__ s2d,
    int N)
{
    __shared__ unsigned short X[16][520];      // [node][dim], +8 pad (2-way max)

    int lane = threadIdx.x & 63;
    int wv = threadIdx.x >> 6;
    int n0 = blockIdx.x * 16;
    int h = lane >> 3;

    #pragma unroll 1
    for (int nl = 0; nl < 4; ++nl) {
        int nloc = wv * 4 + nl;
        int n = n0 + nloc;
        if (n >= N) continue;
        int beg = row_start[n], end = row_start[n + 1];
        float ss = s1s[n * 8 + h];

        float acc[8] = {0.f, 0.f, 0.f, 0.f, 0.f, 0.f, 0.f, 0.f};
        float rs = 0.f;
        int i = beg;
        for (; i + 4 <= end; i += 4) {
            int d0 = csr_dst[i], d1 = csr_dst[i + 1], d2 = csr_dst[i + 2], d3 = csr_dst[i + 3];
            float sd0 = s1d[d0 * 8 + h];
            float sd1 = s1d[d1 * 8 + h];
            float sd2 = s1d[d2 * 8 + h];
            float sd3 = s1d[d3 * 8 + h];
            uint4 w0 = h_q[(long)d0 * 64 + lane];
            uint4 w1 = h_q[(long)d1 * 64 + lane];
            uint4 w2 = h_q[(long)d2 * 64 + lane];
            uint4 w3 = h_q[(long)d3 * 64 + lane];
            float sc0 = ss + sd0, sc1 = ss + sd1, sc2 = ss + sd2, sc3 = ss + sd3;
            float lr0 = sc0 > 0.f ? sc0 : ALPHA * sc0;
            float lr1 = sc1 > 0.f ? sc1 : ALPHA * sc1;
            float lr2 = sc2 > 0.f ? sc2 : ALPHA * sc2;
            float lr3 = sc3 > 0.f ? sc3 : ALPHA * sc3;
            float ev0 = __expf(-lr0), ev1 = __expf(-lr1), ev2 = __expf(-lr2), ev3 = __expf(-lr3);
            rs += (ev0 + ev1) + (ev2 + ev3);
            acc8(acc, ev0, w0);
            acc8(acc, ev1, w1);
            acc8(acc, ev2, w2);
            acc8(acc, ev3, w3);
        }
        for (; i + 2 <= end; i += 2) {
            int d0 = csr_dst[i], d1 = csr_dst[i + 1];
            float sd0 = s1d[d0 * 8 + h];
            float sd1 = s1d[d1 * 8 + h];
            uint4 w0 = h_q[(long)d0 * 64 + lane];
            uint4 w1 = h_q[(long)d1 * 64 + lane];
            float sc0 = ss + sd0, sc1 = ss + sd1;
            float lr0 = sc0 > 0.f ? sc0 : ALPHA * sc0;
            float lr1 = sc1 > 0.f ? sc1 : ALPHA * sc1;
            float ev0 = __expf(-lr0), ev1 = __expf(-lr1);
            rs += ev0 + ev1;
            acc8(acc, ev0, w0);
            acc8(acc, ev1, w1);
        }
        if (i < end) {
            int d = csr_dst[i];
            float sd = s1d[d * 8 + h];
            uint4 wv4 = h_q[(long)d * 64 + lane];
            float sc = ss + sd;
            float lr = sc > 0.f ? sc : ALPHA * sc;
            float ev = __expf(-lr);
            rs += ev;
            acc8(acc, ev, wv4);
        }
        float inv = 1.f / rs;
        unsigned short o[8];
        #pragma unroll
        for (int j = 0; j < 8; ++j) {
            float v = acc[j] * inv;
            v = v > 0.f ? v : __expf(v) - 1.f;   // elu -> xcat element (bf16)
            o[j] = f2bfu(v);
        }
        *(uint4*)&X[nloc][lane * 8] = *(const uint4*)o;
    }
    __syncthreads();

    if (wv == 0) {
        const int q = lane >> 4, m = lane & 15;
        f32x4 pacc = {};
        #pragma unroll
        for (int ks = 0; ks < 16; ++ks) {
            short8 a = *(const short8*)&X[m][ks * 32 + q * 8];
            short8 b = *(const short8*)(wob + (ks << 9) + lane * 8);
            pacc = __builtin_amdgcn_mfma_f32_16x16x32_bf16(a, b, pacc, 0, 0, 0);
        }
        float a1m = (m < NC) ? ao[m] : 0.f;
        float a2m = (m < NC) ? ao[NC + m] : 0.f;
        #pragma unroll
        for (int reg = 0; reg < 4; ++reg) {
            int n = n0 + q * 4 + reg;           // C row = local node
            float pv = pacc[reg];                // C col = class m (0 for m>=NC)
            if (n < N) h2p[(long)n * 16 + m] = pv;
            float p1 = pv * a1m, p2 = pv * a2m;
            #pragma unroll
            for (int off = 1; off < 16; off <<= 1) {
                p1 += __shfl_xor(p1, off);
                p2 += __shfl_xor(p2, off);
            }
            if (m == 0 && n < N) { s2s[n] = p1; s2d[n] = p2; }
        }
    }
}

// ---------- layer-2 CSR gather v2: wave/node, 8 edge slots x 8 dim-lanes ----------
// Lane = (j = lane>>3 edge slot, c2 = lane&7 covering classes 2c2,2c2+1 via float2).
__global__ __launch_bounds__(256) void edge_agg2_kernel(
    const int* __restrict__ row_start, const int* __restrict__ csr_dst,
    const float* __restrict__ h2p,             // [N,16] f32, pad=0
    const float* __restrict__ s_src2, const float* __restrict__ s_dst2,
    void* __restrict__ out, const void* __restrict__ x_raw, int N)
{
    bool isf32 = detect_f32(x_raw);   // all lanes active
    int lane = threadIdx.x & 63;
    int n = blockIdx.x * 4 + (threadIdx.x >> 6);
    if (n >= N) return;
    int c2 = lane & 7, j = lane >> 3;   // 8 edge slots x 8 class-pairs
    int beg = row_start[n], end = row_start[n + 1];
    float ss = s_src2[n];
    float rs = 0.f, a0 = 0.f, a1 = 0.f;
    for (int i0 = beg; i0 < end; i0 += 8) {
        int i = i0 + j;
        if (i < end) {
            int d = csr_dst[i];
            float sc = ss + s_dst2[d];
            float lr = sc > 0.f ? sc : ALPHA * sc;
            float ev = __expf(-lr);
            rs += ev;
            float2 hv = *(const float2*)(h2p + (long)d * 16 + c2 * 2);
            a0 += ev * hv.x;
            a1 += ev * hv.y;
        }
    }
    rs += __shfl_xor(rs, 8);  rs += __shfl_xor(rs, 16);  rs += __shfl_xor(rs, 32);
    a0 += __shfl_xor(a0, 8);  a0 += __shfl_xor(a0, 16);  a0 += __shfl_xor(a0, 32);
    a1 += __shfl_xor(a1, 8);  a1 += __shfl_xor(a1, 16);  a1 += __shfl_xor(a1, 32);
    float inv = 1.f / rs;
    float v0 = a0 * inv, v1 = a1 * inv;
    v0 = v0 > 0.f ? v0 : __expf(v0) - 1.f;       // elu
    v1 = v1 > 0.f ? v1 : __expf(v1) - 1.f;
    // log-softmax over the 10 valid classes (c2<5 holds valid pairs)
    bool valid = (c2 * 2 + 1 < NC);
    float vm = valid ? fmaxf(v0, v1) : -1e30f;
    #pragma unroll
    for (int off = 1; off < 8; off <<= 1) vm = fmaxf(vm, __shfl_xor(vm, off, 64));
    float ex = valid ? (__expf(v0 - vm) + __expf(v1 - vm)) : 0.f;
    #pragma unroll
    for (int off = 1; off < 8; off <<= 1) ex += __shfl_xor(ex, off, 64);
    float lse = vm + logf(ex);
    if (valid && j == 0) {
        if (isf32) {
            *(float2*)((float*)out + (long)n * NC + c2 * 2) = make_float2(v0 - lse, v1 - lse);
        } else {
            unsigned int o = (unsigned int)f2bfu(v0 - lse) | ((unsigned int)f2bfu(v1 - lse) << 16);
            *(unsigned int*)((unsigned short*)out + (long)n * NC + c2 * 2) = o;
        }
    }
}

extern "C" void kernel_launch(void* const* d_in, const int* in_sizes, int n_in,
                              void* d_out, int out_size, void* d_ws, size_t ws_size,
                              hipStream_t stream)
{
    const void* x_raw  = d_in[0];
    const int*  esrc   = (const int*)d_in[1];
    const int*  edst   = (const int*)d_in[2];
    const void* Wh_raw = d_in[3];
    const void* ah_raw = d_in[4];
    const void* Wo_raw = d_in[5];
    const void* ao_raw = d_in[6];

    const int N = in_sizes[0] / F_IN;
    const int E = in_sizes[1];

    char* ws = (char*)d_ws;
    size_t off = 0;
    auto alloc = [&](size_t bytes) -> void* {
        void* p = ws + off;
        off = (off + bytes + 255) & ~(size_t)255;
        return p;
    };
    // zero-init region first (counts only -> ONE memset)
    int*            counts    = (int*)           alloc((size_t)N * 4);

    unsigned short* x_bf      = (unsigned short*)alloc((size_t)N * F_IN * 2);
    unsigned short* wh_f      = (unsigned short*)alloc((size_t)H_HEADS * D_HID * F_IN * 2);
    float*          ah32      = (float*)         alloc((size_t)H_HEADS * 2 * D_HID * 4);
    unsigned short* wob_f     = (unsigned short*)alloc((size_t)16 * 64 * 8 * 2);
    float*          ao32      = (float*)         alloc((size_t)2 * NC * 4);
    unsigned short* h_bf      = (unsigned short*)alloc((size_t)N * 512 * 2);
    float*          s1s       = (float*)         alloc((size_t)N * 8 * 4);
    float*          s1d       = (float*)         alloc((size_t)N * 8 * 4);
    float*          h2p       = (float*)         alloc((size_t)N * 16 * 4);
    float*          s2s       = (float*)         alloc((size_t)N * 4);
    float*          s2d       = (float*)         alloc((size_t)N * 4);
    int*            row_start = (int*)           alloc((size_t)(N + 1) * 4);
    int*            csr_dst   = (int*)           alloc((size_t)E * 4);
    int*            pos_e     = (int*)           alloc((size_t)E * 4);
    (void)ws_size;

    hipMemsetAsync(counts, 0, (size_t)N * 4, stream);

    // fused converts + histogram (dtype detected per-block from x sample)
    int bx = (int)(((long)N * F_IN / 8 + 255) / 256);      // x blocks
    int bw = bx + (H_HEADS * F_IN * D_HID) / 256;          // + W frag blocks
    int ba = bw + (H_HEADS * 2 * D_HID) / 256;             // + ah blocks
    int bo = ba + (16 * 64 * 8) / 256;                     // + wob frag blocks; bo = ao block
    int nb = bo + 1 + (E + 255) / 256;                     // + hist blocks
    prep_kernel<<<nb, 256, 0, stream>>>(x_raw, x_bf, Wh_raw, wh_f, ah_raw, ah32,
                                        Wo_raw, wob_f, ao_raw, ao32,
                                        esrc, counts, pos_e, N, E, bx, bw, ba, bo);
    scan_kernel<<<1, SCAN_T, 0, stream>>>(counts, row_start, N, E);
    scatter_kernel<<<(E + 255) / 256, 256, 0, stream>>>(esrc, edst, row_start, pos_e, csr_dst, E);

    // layer 1 (gemm) -> layer-1 aggregation with MFMA-batched layer-2 projection
    gemm1_kernel<<<(N + 63) / 64, 256, 0, stream>>>(x_bf, wh_f, ah32, h_bf, s1s, s1d, N);
    edge_agg1_kernel<<<(N + 15) / 16, 256, 0, stream>>>(row_start, csr_dst, s1s, s1d,
                                                        (const uint4*)h_bf, wob_f, ao32,
                                                        h2p, s2s, s2d, N);

    // layer-2 aggregation + log-softmax
    edge_agg2_kernel<<<(N + 3) / 4, 256, 0, stream>>>(row_start, csr_dst, h2p, s2s, s2d, d_out, x_raw, N);
}

// Round 5
// 374.739 us; speedup vs baseline: 2.7198x; 1.1717x over previous
//
#include <hip/hip_runtime.h>
#include <hip/hip_bf16.h>

#define F_IN    256
#define D_HID   64
#define H_HEADS 8
#define NC      10
#define ALPHA   0.2f
#define SCAN_T  1024

typedef __attribute__((ext_vector_type(8))) short short8;
typedef __attribute__((ext_vector_type(4))) float f32x4;
typedef __attribute__((ext_vector_type(2))) float f32x2;

// ---------- bf16 helpers ----------
__device__ __forceinline__ float bfu2f(unsigned short u) {
    union { float f; unsigned int i; } c; c.i = ((unsigned int)u) << 16; return c.f;
}
__device__ __forceinline__ unsigned short f2bfu(float f) {
    union { float f; unsigned int i; } c; c.f = f;
    unsigned int x = c.i;
    x += 0x7fffu + ((x >> 16) & 1u);   // round-to-nearest-even
    return (unsigned short)(x >> 16);
}

// ---------- inline dtype detection (f32 vs bf16 storage), wave-uniform ----------
// MUST run with ALL 64 lanes active (__ballot counts active lanes only).
__device__ __forceinline__ bool detect_f32(const void* xraw) {
    unsigned int w = ((const unsigned int*)xraw)[threadIdx.x & 63];
    unsigned int e = (w >> 7) & 0xffu;
    unsigned long long m = __ballot(e >= 140u);
    return __popcll(m) > 8;
}

// ---------- fused prep: all input conversions + edge histogram (+pos stash) ----------
__global__ __launch_bounds__(256) void prep_kernel(
    const void* __restrict__ x_raw,  unsigned short* __restrict__ x_bf,
    const void* __restrict__ Wh_raw, unsigned short* __restrict__ wh_f,
    const void* __restrict__ ah_raw, float* __restrict__ ah32,
    const void* __restrict__ Wo_raw, unsigned short* __restrict__ wob_f,
    const void* __restrict__ ao_raw, float* __restrict__ ao32,
    const int* __restrict__ esrc, int* __restrict__ counts, int* __restrict__ pos_e,
    int N, int E, int bx, int bw, int ba, int bo)
{
    int b = blockIdx.x;
    bool isf32 = detect_f32(x_raw);   // all lanes active here
    if (b < bx) {                       // x -> bf16, 8 elems/thread
        long i = (long)b * 256 + threadIdx.x;
        long n8 = (long)N * F_IN / 8;
        if (i < n8) {
            unsigned short o[8];
            if (isf32) {
                const float4* s = (const float4*)x_raw + i * 2;
                float4 a = s[0], bb = s[1];
                o[0] = f2bfu(a.x);  o[1] = f2bfu(a.y);
                o[2] = f2bfu(a.z);  o[3] = f2bfu(a.w);
                o[4] = f2bfu(bb.x); o[5] = f2bfu(bb.y);
                o[6] = f2bfu(bb.z); o[7] = f2bfu(bb.w);
            } else {
                *(uint4*)o = ((const uint4*)x_raw)[i];
            }
            *(uint4*)(x_bf + i * 8) = *(uint4*)o;
        }
    } else if (b < bw) {                // W_heads [8][256][64] -> fragment-major bf16
        int i = (b - bx) * 256 + threadIdx.x;
        int d = i & 63, k = (i >> 6) & 255, h = i >> 14;
        float v = isf32 ? ((const float*)Wh_raw)[i] : bfu2f(((const unsigned short*)Wh_raw)[i]);
        int ks = k >> 5, q = (k >> 3) & 3, j = k & 7;
        int c = d >> 4, m = d & 15;
        wh_f[(((h * 8 + ks) * 4 + c) << 9) + (q * 16 + m) * 8 + j] = f2bfu(v);
    } else if (b < ba) {                // a_heads -> f32 (1024)
        int i = (b - bw) * 256 + threadIdx.x;
        ah32[i] = isf32 ? ((const float*)ah_raw)[i] : bfu2f(((const unsigned short*)ah_raw)[i]);
    } else if (b < bo) {                // W_out [512,10] -> fragment-major bf16, cols padded to 16
        int i = (b - ba) * 256 + threadIdx.x;   // 0..8191 = (ks<<9) + L*8 + j
        int j = i & 7, L = (i >> 3) & 63, ks = i >> 9;
        int q = L >> 4, m = L & 15;
        int k = ks * 32 + q * 8 + j;
        float v = 0.f;
        if (m < NC)
            v = isf32 ? ((const float*)Wo_raw)[k * NC + m] : bfu2f(((const unsigned short*)Wo_raw)[k * NC + m]);
        wob_f[i] = f2bfu(v);
    } else if (b == bo) {               // a_out -> f32 (20)
        int i = threadIdx.x;
        if (i < 2 * NC)
            ao32[i] = isf32 ? ((const float*)ao_raw)[i] : bfu2f(((const unsigned short*)ao_raw)[i]);
    } else {                            // edge histogram + stash row-local position
        int e = (b - bo - 1) * 256 + threadIdx.x;
        if (e < E) {
            int s = esrc[e];
            int pos = atomicAdd(&counts[s], 1);
            pos_e[e] = pos;
        }
    }
}

// ---------- CSR scan ----------
__global__ __launch_bounds__(SCAN_T) void scan_kernel(
    const int* __restrict__ counts, int* __restrict__ row_start, int N, int E)
{
    __shared__ int sums[SCAN_T];
    int t = threadIdx.x;
    int chunk = (N + SCAN_T - 1) / SCAN_T;
    int b = t * chunk, e = min(b + chunk, N);
    int s = 0;
    for (int i = b; i < e; ++i) s += counts[i];
    sums[t] = s;
    __syncthreads();
    for (int off = 1; off < SCAN_T; off <<= 1) {
        int u = (t >= off) ? sums[t - off] : 0;
        __syncthreads();
        sums[t] += u;
        __syncthreads();
    }
    int running = sums[t] - s;
    for (int i = b; i < e; ++i) { row_start[i] = running; running += counts[i]; }
    if (t == SCAN_T - 1) row_start[N] = E;
}

// ---------- CSR scatter: no atomics (positions stashed by prep) ----------
__global__ __launch_bounds__(256) void scatter_kernel(
    const int* __restrict__ src, const int* __restrict__ dst,
    const int* __restrict__ row_start, const int* __restrict__ pos_e,
    int* __restrict__ csr_dst, int E)
{
    int e = blockIdx.x * 256 + threadIdx.x;
    if (e >= E) return;
    int s = src[e];
    csr_dst[row_start[s] + pos_e[e]] = dst[e];
}

// ---------- layer-1 MFMA GEMM + fused attn1; h stored as FP8 e4m3 ----------
// Scores s1s/s1d computed from the f32 accumulator (exact attention weights);
// only the gathered payload h is quantized to fp8 (halves the 51.2 MB table).
__global__ __launch_bounds__(256) void gemm1_kernel(
    const unsigned short* __restrict__ x_bf,   // [N,256] bf16
    const unsigned short* __restrict__ wh_f,   // fragment-major bf16
    const float* __restrict__ ah,              // [8,128] f32
    unsigned char* __restrict__ h8,            // [N,512] fp8 out
    float* __restrict__ s1s, float* __restrict__ s1d, int N)
{
    __shared__ unsigned char Os8[64][80];      // fp8 staging, 80 B rows (16-B aligned)

    const int t = threadIdx.x;
    const int w = t >> 6, lane = t & 63;
    const int q = lane >> 4, m = lane & 15;
    const int n0 = blockIdx.x * 64;

    int r = n0 + 16 * w + m;
    const unsigned short* xr = x_bf + (long)(r < N ? r : N - 1) * 256;
    short8 afrag[8];
    #pragma unroll
    for (int ks = 0; ks < 8; ++ks)
        afrag[ks] = *(const short8*)(xr + ks * 32 + q * 8);

    #pragma unroll
    for (int h = 0; h < 8; ++h) {
        f32x4 acc[4] = {};
        const unsigned short* Bh = wh_f + (((long)h * 32) << 9);
        #pragma unroll
        for (int ks = 0; ks < 8; ++ks) {
            #pragma unroll
            for (int c = 0; c < 4; ++c) {
                short8 b = *(const short8*)(Bh + (((ks * 4 + c) << 9) + lane * 8));
                acc[c] = __builtin_amdgcn_mfma_f32_16x16x32_bf16(afrag[ks], b, acc[c], 0, 0, 0);
            }
        }

        const float* a1 = ah + h * 128;
        float a1m = a1[m], a1m16 = a1[16 + m], a1m32 = a1[32 + m], a1m48 = a1[48 + m];
        float a2m = a1[64 + m], a2m16 = a1[80 + m], a2m32 = a1[96 + m], a2m48 = a1[112 + m];
        #pragma unroll
        for (int reg = 0; reg < 4; ++reg) {
            float p1 = acc[0][reg] * a1m + acc[1][reg] * a1m16 + acc[2][reg] * a1m32 + acc[3][reg] * a1m48;
            float p2 = acc[0][reg] * a2m + acc[1][reg] * a2m16 + acc[2][reg] * a2m32 + acc[3][reg] * a2m48;
            #pragma unroll
            for (int off = 1; off < 16; off <<= 1) {
                p1 += __shfl_xor(p1, off);
                p2 += __shfl_xor(p2, off);
            }
            int row = n0 + 16 * w + q * 4 + reg;
            if (m == 0 && row < N) {
                s1s[row * 8 + h] = p1;
                s1d[row * 8 + h] = p2;
            }
        }

        // pack f32 -> fp8 pairs via lane-pair shuffle (even m packs dims m,m+1)
        #pragma unroll
        for (int c = 0; c < 4; ++c) {
            #pragma unroll
            for (int reg = 0; reg < 4; ++reg) {
                float a = acc[c][reg];
                float b = __shfl_xor(a, 1);
                if (!(m & 1)) {
                    unsigned int p = __builtin_amdgcn_cvt_pk_fp8_f32(a, b, 0u, false);
                    *(unsigned short*)&Os8[16 * w + q * 4 + reg][c * 16 + m] = (unsigned short)(p & 0xffffu);
                }
            }
        }
        // writeback: 16 rows x 64 B per wave per head
        {
            int row = lane >> 2, q4 = lane & 3;
            int rr = n0 + 16 * w + row;
            if (rr < N)
                *(uint4*)(h8 + (long)rr * 512 + h * 64 + q4 * 16) =
                    *(const uint4*)&Os8[16 * w + row][q4 * 16];
        }
    }
}

// ---------- layer-1 CSR gather (fp8 payload) + MFMA-batched layer-2 projection ----------
// Block = 4 waves x 4 nodes. Per edge: 512 B row (8 fp8/lane), hardware
// v_cvt_pk_f32_fp8 decode (4 instrs per 8 dims). Structure proven in r4.
__device__ __forceinline__ void acc8f8(float* acc, float ev, uint2 v) {
    f32x2 f0 = __builtin_amdgcn_cvt_pk_f32_fp8(v.x, false);
    f32x2 f1 = __builtin_amdgcn_cvt_pk_f32_fp8(v.x, true);
    f32x2 f2 = __builtin_amdgcn_cvt_pk_f32_fp8(v.y, false);
    f32x2 f3 = __builtin_amdgcn_cvt_pk_f32_fp8(v.y, true);
    acc[0] += ev * f0.x; acc[1] += ev * f0.y;
    acc[2] += ev * f1.x; acc[3] += ev * f1.y;
    acc[4] += ev * f2.x; acc[5] += ev * f2.y;
    acc[6] += ev * f3.x; acc[7] += ev * f3.y;
}

__global__ __launch_bounds__(256) void edge_agg1_kernel(
    const int* __restrict__ row_start, const int* __restrict__ csr_dst,
    const float* __restrict__ s1s, const float* __restrict__ s1d,
    const uint2* __restrict__ h8q,             // [N*64] uint2 (= [N,512] fp8)
    const unsigned short* __restrict__ wob,    // [16][64][8] bf16 frag-major (Wo)
    const float* __restrict__ ao,              // [20] f32
    float* __restrict__ h2p,                   // [N,16] f32, pad=0
    float* __restrict__ s2s, float* __restrict__ s2d,
    int N)
{
    __shared__ unsigned short X[16][520];      // [node][dim] bf16, +8 pad

    int lane = threadIdx.x & 63;
    int wv = threadIdx.x >> 6;
    int n0 = blockIdx.x * 16;
    int h = lane >> 3;

    #pragma unroll 1
    for (int nl = 0; nl < 4; ++nl) {
        int nloc = wv * 4 + nl;
        int n = n0 + nloc;
        if (n >= N) continue;
        int beg = row_start[n], end = row_start[n + 1];
        float ss = s1s[n * 8 + h];

        float acc[8] = {0.f, 0.f, 0.f, 0.f, 0.f, 0.f, 0.f, 0.f};
        float rs = 0.f;
        int i = beg;
        for (; i + 4 <= end; i += 4) {
            int d0 = csr_dst[i], d1 = csr_dst[i + 1], d2 = csr_dst[i + 2], d3 = csr_dst[i + 3];
            float sd0 = s1d[d0 * 8 + h];
            float sd1 = s1d[d1 * 8 + h];
            float sd2 = s1d[d2 * 8 + h];
            float sd3 = s1d[d3 * 8 + h];
            uint2 w0 = h8q[(long)d0 * 64 + lane];
            uint2 w1 = h8q[(long)d1 * 64 + lane];
            uint2 w2 = h8q[(long)d2 * 64 + lane];
            uint2 w3 = h8q[(long)d3 * 64 + lane];
            float sc0 = ss + sd0, sc1 = ss + sd1, sc2 = ss + sd2, sc3 = ss + sd3;
            float lr0 = sc0 > 0.f ? sc0 : ALPHA * sc0;
            float lr1 = sc1 > 0.f ? sc1 : ALPHA * sc1;
            float lr2 = sc2 > 0.f ? sc2 : ALPHA * sc2;
            float lr3 = sc3 > 0.f ? sc3 : ALPHA * sc3;
            float ev0 = __expf(-lr0), ev1 = __expf(-lr1), ev2 = __expf(-lr2), ev3 = __expf(-lr3);
            rs += (ev0 + ev1) + (ev2 + ev3);
            acc8f8(acc, ev0, w0);
            acc8f8(acc, ev1, w1);
            acc8f8(acc, ev2, w2);
            acc8f8(acc, ev3, w3);
        }
        for (; i + 2 <= end; i += 2) {
            int d0 = csr_dst[i], d1 = csr_dst[i + 1];
            float sd0 = s1d[d0 * 8 + h];
            float sd1 = s1d[d1 * 8 + h];
            uint2 w0 = h8q[(long)d0 * 64 + lane];
            uint2 w1 = h8q[(long)d1 * 64 + lane];
            float sc0 = ss + sd0, sc1 = ss + sd1;
            float lr0 = sc0 > 0.f ? sc0 : ALPHA * sc0;
            float lr1 = sc1 > 0.f ? sc1 : ALPHA * sc1;
            float ev0 = __expf(-lr0), ev1 = __expf(-lr1);
            rs += ev0 + ev1;
            acc8f8(acc, ev0, w0);
            acc8f8(acc, ev1, w1);
        }
        if (i < end) {
            int d = csr_dst[i];
            float sd = s1d[d * 8 + h];
            uint2 wv4 = h8q[(long)d * 64 + lane];
            float sc = ss + sd;
            float lr = sc > 0.f ? sc : ALPHA * sc;
            float ev = __expf(-lr);
            rs += ev;
            acc8f8(acc, ev, wv4);
        }
        float inv = 1.f / rs;
        unsigned short o[8];
        #pragma unroll
        for (int j = 0; j < 8; ++j) {
            float v = acc[j] * inv;
            v = v > 0.f ? v : __expf(v) - 1.f;   // elu -> xcat element (bf16)
            o[j] = f2bfu(v);
        }
        *(uint4*)&X[nloc][lane * 8] = *(const uint4*)o;
    }
    __syncthreads();

    if (wv == 0) {
        const int q = lane >> 4, m = lane & 15;
        f32x4 pacc = {};
        #pragma unroll
        for (int ks = 0; ks < 16; ++ks) {
            short8 a = *(const short8*)&X[m][ks * 32 + q * 8];
            short8 b = *(const short8*)(wob + (ks << 9) + lane * 8);
            pacc = __builtin_amdgcn_mfma_f32_16x16x32_bf16(a, b, pacc, 0, 0, 0);
        }
        float a1m = (m < NC) ? ao[m] : 0.f;
        float a2m = (m < NC) ? ao[NC + m] : 0.f;
        #pragma unroll
        for (int reg = 0; reg < 4; ++reg) {
            int n = n0 + q * 4 + reg;           // C row = local node
            float pv = pacc[reg];                // C col = class m (0 for m>=NC)
            if (n < N) h2p[(long)n * 16 + m] = pv;
            float p1 = pv * a1m, p2 = pv * a2m;
            #pragma unroll
            for (int off = 1; off < 16; off <<= 1) {
                p1 += __shfl_xor(p1, off);
                p2 += __shfl_xor(p2, off);
            }
            if (m == 0 && n < N) { s2s[n] = p1; s2d[n] = p2; }
        }
    }
}

// ---------- layer-2 CSR gather v2: wave/node, 8 edge slots x 8 dim-lanes ----------
// Lane = (j = lane>>3 edge slot, c2 = lane&7 covering classes 2c2,2c2+1 via float2).
__global__ __launch_bounds__(256) void edge_agg2_kernel(
    const int* __restrict__ row_start, const int* __restrict__ csr_dst,
    const float* __restrict__ h2p,             // [N,16] f32, pad=0
    const float* __restrict__ s_src2, const float* __restrict__ s_dst2,
    void* __restrict__ out, const void* __restrict__ x_raw, int N)
{
    bool isf32 = detect_f32(x_raw);   // all lanes active
    int lane = threadIdx.x & 63;
    int n = blockIdx.x * 4 + (threadIdx.x >> 6);
    if (n >= N) return;
    int c2 = lane & 7, j = lane >> 3;   // 8 edge slots x 8 class-pairs
    int beg = row_start[n], end = row_start[n + 1];
    float ss = s_src2[n];
    float rs = 0.f, a0 = 0.f, a1 = 0.f;
    for (int i0 = beg; i0 < end; i0 += 8) {
        int i = i0 + j;
        if (i < end) {
            int d = csr_dst[i];
            float sc = ss + s_dst2[d];
            float lr = sc > 0.f ? sc : ALPHA * sc;
            float ev = __expf(-lr);
            rs += ev;
            float2 hv = *(const float2*)(h2p + (long)d * 16 + c2 * 2);
            a0 += ev * hv.x;
            a1 += ev * hv.y;
        }
    }
    rs += __shfl_xor(rs, 8);  rs += __shfl_xor(rs, 16);  rs += __shfl_xor(rs, 32);
    a0 += __shfl_xor(a0, 8);  a0 += __shfl_xor(a0, 16);  a0 += __shfl_xor(a0, 32);
    a1 += __shfl_xor(a1, 8);  a1 += __shfl_xor(a1, 16);  a1 += __shfl_xor(a1, 32);
    float inv = 1.f / rs;
    float v0 = a0 * inv, v1 = a1 * inv;
    v0 = v0 > 0.f ? v0 : __expf(v0) - 1.f;       // elu
    v1 = v1 > 0.f ? v1 : __expf(v1) - 1.f;
    // log-softmax over the 10 valid classes (c2<5 holds valid pairs)
    bool valid = (c2 * 2 + 1 < NC);
    float vm = valid ? fmaxf(v0, v1) : -1e30f;
    #pragma unroll
    for (int off = 1; off < 8; off <<= 1) vm = fmaxf(vm, __shfl_xor(vm, off, 64));
    float ex = valid ? (__expf(v0 - vm) + __expf(v1 - vm)) : 0.f;
    #pragma unroll
    for (int off = 1; off < 8; off <<= 1) ex += __shfl_xor(ex, off, 64);
    float lse = vm + logf(ex);
    if (valid && j == 0) {
        if (isf32) {
            *(float2*)((float*)out + (long)n * NC + c2 * 2) = make_float2(v0 - lse, v1 - lse);
        } else {
            unsigned int o = (unsigned int)f2bfu(v0 - lse) | ((unsigned int)f2bfu(v1 - lse) << 16);
            *(unsigned int*)((unsigned short*)out + (long)n * NC + c2 * 2) = o;
        }
    }
}

extern "C" void kernel_launch(void* const* d_in, const int* in_sizes, int n_in,
                              void* d_out, int out_size, void* d_ws, size_t ws_size,
                              hipStream_t stream)
{
    const void* x_raw  = d_in[0];
    const int*  esrc   = (const int*)d_in[1];
    const int*  edst   = (const int*)d_in[2];
    const void* Wh_raw = d_in[3];
    const void* ah_raw = d_in[4];
    const void* Wo_raw = d_in[5];
    const void* ao_raw = d_in[6];

    const int N = in_sizes[0] / F_IN;
    const int E = in_sizes[1];

    char* ws = (char*)d_ws;
    size_t off = 0;
    auto alloc = [&](size_t bytes) -> void* {
        void* p = ws + off;
        off = (off + bytes + 255) & ~(size_t)255;
        return p;
    };
    // zero-init region first (counts only -> ONE memset)
    int*            counts    = (int*)           alloc((size_t)N * 4);

    unsigned short* x_bf      = (unsigned short*)alloc((size_t)N * F_IN * 2);
    unsigned short* wh_f      = (unsigned short*)alloc((size_t)H_HEADS * D_HID * F_IN * 2);
    float*          ah32      = (float*)         alloc((size_t)H_HEADS * 2 * D_HID * 4);
    unsigned short* wob_f     = (unsigned short*)alloc((size_t)16 * 64 * 8 * 2);
    float*          ao32      = (float*)         alloc((size_t)2 * NC * 4);
    unsigned char*  h8        = (unsigned char*) alloc((size_t)N * 512);
    float*          s1s       = (float*)         alloc((size_t)N * 8 * 4);
    float*          s1d       = (float*)         alloc((size_t)N * 8 * 4);
    float*          h2p       = (float*)         alloc((size_t)N * 16 * 4);
    float*          s2s       = (float*)         alloc((size_t)N * 4);
    float*          s2d       = (float*)         alloc((size_t)N * 4);
    int*            row_start = (int*)           alloc((size_t)(N + 1) * 4);
    int*            csr_dst   = (int*)           alloc((size_t)E * 4);
    int*            pos_e     = (int*)           alloc((size_t)E * 4);
    (void)ws_size;

    hipMemsetAsync(counts, 0, (size_t)N * 4, stream);

    // fused converts + histogram (dtype detected per-block from x sample)
    int bx = (int)(((long)N * F_IN / 8 + 255) / 256);      // x blocks
    int bw = bx + (H_HEADS * F_IN * D_HID) / 256;          // + W frag blocks
    int ba = bw + (H_HEADS * 2 * D_HID) / 256;             // + ah blocks
    int bo = ba + (16 * 64 * 8) / 256;                     // + wob frag blocks; bo = ao block
    int nb = bo + 1 + (E + 255) / 256;                     // + hist blocks
    prep_kernel<<<nb, 256, 0, stream>>>(x_raw, x_bf, Wh_raw, wh_f, ah_raw, ah32,
                                        Wo_raw, wob_f, ao_raw, ao32,
                                        esrc, counts, pos_e, N, E, bx, bw, ba, bo);
    scan_kernel<<<1, SCAN_T, 0, stream>>>(counts, row_start, N, E);
    scatter_kernel<<<(E + 255) / 256, 256, 0, stream>>>(esrc, edst, row_start, pos_e, csr_dst, E);

    // layer 1 (gemm, fp8 h) -> layer-1 aggregation with MFMA-batched layer-2 projection
    gemm1_kernel<<<(N + 63) / 64, 256, 0, stream>>>(x_bf, wh_f, ah32, h8, s1s, s1d, N);
    edge_agg1_kernel<<<(N + 15) / 16, 256, 0, stream>>>(row_start, csr_dst, s1s, s1d,
                                                        (const uint2*)h8, wob_f, ao32,
                                                        h2p, s2s, s2d, N);

    // layer-2 aggregation + log-softmax
    edge_agg2_kernel<<<(N + 3) / 4, 256, 0, stream>>>(row_start, csr_dst, h2p, s2s, s2d, d_out, x_raw, N);
}